// Round 4
// baseline (206.968 us; speedup 1.0000x reference)
//
#include <hip/hip_runtime.h>
#include <math.h>

typedef unsigned short u16;
typedef unsigned int   u32;
typedef __attribute__((ext_vector_type(8))) short bf16x8;
typedef __attribute__((ext_vector_type(4))) float floatx4;
typedef __attribute__((ext_vector_type(4))) _Float16 halfx4;
typedef __attribute__((ext_vector_type(2))) unsigned int uintx2;

// B=2, S=2048, D=1024, H=16, Dh=64, M=B*S=4096
#define SEQ 2048
#define DM  1024
#define NH  16
#define DH  64
#define MM  4096
#define QSCALE 0.18033688011112042f   // 0.125 * log2(e), folded into Q

__device__ __forceinline__ u16 f2bf(float f) {
    u32 u = __builtin_bit_cast(u32, f);
    u += 0x7fffu + ((u >> 16) & 1u);
    return (u16)(u >> 16);
}

__device__ __forceinline__ void async16(const void* g, void* l) {
    __builtin_amdgcn_global_load_lds(
        (const __attribute__((address_space(1))) void*)g,
        (__attribute__((address_space(3))) void*)l, 16, 0, 0);
}

// ---------------- prep: fp32 -> bf16 shuffled layout + RoPE table -------------------
// Shuffled layout: tile (rowblk=row/16, ktile=col/32); element [m=lm][k=quad*8+j]
// stored flat at (rowblk*32 + ktile)*512 + lane*8 + j. One dwordx4/lane per fragment.
// First 256 linear blocks additionally fill the RoPE table (2048x32 float2).
__global__ __launch_bounds__(256) void prep_kernel(const float* __restrict__ x,
                                                   const float* __restrict__ w0,
                                                   const float* __restrict__ w1,
                                                   const float* __restrict__ w2,
                                                   const float* __restrict__ w3,
                                                   u16* __restrict__ Xsh,
                                                   u16* __restrict__ Wsh,
                                                   const int* __restrict__ pos,
                                                   float2* __restrict__ tab) {
    const int bid = blockIdx.x, cb = blockIdx.y, tid = threadIdx.x;

    // RoPE table side-job
    int lin = bid * 16 + cb;
    if (lin < 256) {
        int i = lin * 256 + tid;       // 65536 = 2048*32
        int p = i >> 5, d2 = i & 31;
        float freq = __expf(-(float)d2 * (9.2103403719761836f / 32.0f));
        float sv, cv;
        sincosf((float)pos[p] * freq, &sv, &cv);
        tab[i] = make_float2(cv, sv);
    }

    const float* src; u16* dst; int row0;
    if (bid < 64) { src = x; dst = Xsh; row0 = bid * 64; }
    else {
        int wi = (bid - 64) >> 4;
        src = (wi == 0) ? w0 : (wi == 1) ? w1 : (wi == 2) ? w2 : w3;
        dst = Wsh + (size_t)wi * DM * DM;
        row0 = ((bid - 64) & 15) * 64;
    }
    __shared__ __align__(16) u16 t[64 * 64];   // 8-elem chunks XOR-swizzled by row&7
#pragma unroll
    for (int rep = 0; rep < 4; ++rep) {
        int f = rep * 256 + tid;
        int r = f >> 4, c4 = f & 15;
        float4 v = *(const float4*)&src[(size_t)(row0 + r) * DM + cb * 64 + c4 * 4];
        uint2 pk;
        pk.x = (u32)f2bf(v.x) | ((u32)f2bf(v.y) << 16);
        pk.y = (u32)f2bf(v.z) | ((u32)f2bf(v.w) << 16);
        int ch = (c4 >> 1) ^ (r & 7);
        *(uint2*)&t[r * 64 + ch * 8 + (c4 & 1) * 4] = pk;
    }
    __syncthreads();
#pragma unroll
    for (int rep = 0; rep < 2; ++rep) {
        int s = rep * 256 + tid;
        int tile = s >> 6, l = s & 63;
        int mt = tile >> 1, kt = tile & 1, lm = l & 15, quad = l >> 4;
        int m = mt * 16 + lm;
        uint4 v = *(const uint4*)&t[m * 64 + ((kt * 4 + quad) ^ (m & 7)) * 8];
        size_t rowblk = (size_t)(row0 >> 4) + mt;
        size_t ktile  = cb * 2 + kt;
        *(uint4*)&dst[(rowblk * 32 + ktile) * 512 + l * 8] = v;
    }
}

// ---------------- fused-z NT GEMM, LDS double-buffered, stage-ahead -----------------
// C_z[M,1024] = A * W_z^T for z in [0,NZ). Block tile 64 rows x 128 cols, 4 waves,
// wave w owns cols [n0+w*32, +32). BK=32 (1 ktile/step), 32 K-steps.
// Both operands staged via global_load_lds into DOUBLE-buffered LDS; stage for step
// it+1 is issued BEFORE computing step it, so the vmcnt drain at the (single)
// end-of-iter barrier lands after 24 (NZ=3) MFMAs of latency hiding.
// A is loaded once per block (shared by 4 waves); with NZ=3 each staged byte feeds
// 3x the MFMAs (Q,K,V share A). Epilogues: RoPE on z<2, QSCALE on z==0; z==2 writes
// V^T as PV A-fragment chunks (the acc tile IS the fragment); OUTF32 (Wo) writes fp32.
template<int NZ, bool OUTF32>
__global__ __launch_bounds__(256, 2) void gemm_f(const u16* __restrict__ Ash,
                                                 const u16* __restrict__ Wbase,
                                                 u16* __restrict__ outbf,
                                                 float* __restrict__ outf,
                                                 _Float16* __restrict__ vtout,
                                                 const float2* __restrict__ ropetab) {
    const int m0 = blockIdx.x * 64, n0 = blockIdx.y * 128;
    const int tid = threadIdx.x, lane = tid & 63, w = tid >> 6;
    const int lm = lane & 15, quad = lane >> 4;
    const int rb0 = m0 >> 4;        // 4 rowblks per block
    const int cb0 = n0 >> 4;        // 8 colblks per block

    __shared__ __align__(16) u16 lsA[2][4 * 512];        // 2 x 4KB
    __shared__ __align__(16) u16 lsB[2][NZ * 8 * 512];   // 2 x NZ*8KB

    // per-wave staging sources (chunk stride between ktiles = 512 elems)
    const u16* aSrc = Ash + ((size_t)(rb0 + w) * 32) * 512 + lane * 8;
    constexpr int NPW = NZ * 2;     // B pieces per wave (NZ*8 pieces / 4 waves)
    const u16* bSrc[NPW];
#pragma unroll
    for (int j = 0; j < NPW; ++j) {
        int p = w * NPW + j, z = p >> 3, cb8 = p & 7;
        bSrc[j] = Wbase + (size_t)z * (DM * DM)
                + ((size_t)(cb0 + cb8) * 32) * 512 + lane * 8;
    }

    auto stage = [&](int buf, int it) {
        async16(aSrc + (size_t)it * 512, &lsA[buf][w * 512 + lane * 8]);
#pragma unroll
        for (int j = 0; j < NPW; ++j)
            async16(bSrc[j] + (size_t)it * 512,
                    &lsB[buf][(w * NPW + j) * 512 + lane * 8]);
    };

    floatx4 acc[NZ][4][2];
    const floatx4 z4 = {0.f, 0.f, 0.f, 0.f};
#pragma unroll
    for (int z = 0; z < NZ; ++z)
#pragma unroll
        for (int mt = 0; mt < 4; ++mt)
#pragma unroll
            for (int nt = 0; nt < 2; ++nt) acc[z][mt][nt] = z4;

    stage(0, 0);
    __syncthreads();

#pragma unroll 2
    for (int it = 0; it < 32; ++it) {
        if (it < 31) stage((it + 1) & 1, it + 1);   // stage-ahead (hidden under MFMAs)
        const u16* La = &lsA[it & 1][0];
        const u16* Lb = &lsB[it & 1][0];
        bf16x8 a[4], b[NZ][2];
#pragma unroll
        for (int mt = 0; mt < 4; ++mt)
            a[mt] = *(const bf16x8*)&La[mt * 512 + lane * 8];
#pragma unroll
        for (int z = 0; z < NZ; ++z)
#pragma unroll
            for (int nt = 0; nt < 2; ++nt)
                b[z][nt] = *(const bf16x8*)&Lb[(z * 8 + w * 2 + nt) * 512 + lane * 8];
#pragma unroll
        for (int z = 0; z < NZ; ++z)
#pragma unroll
            for (int mt = 0; mt < 4; ++mt)
#pragma unroll
                for (int nt = 0; nt < 2; ++nt)
                    acc[z][mt][nt] = __builtin_amdgcn_mfma_f32_16x16x32_bf16(
                        a[mt], b[z][nt], acc[z][mt][nt], 0, 0, 0);
        __syncthreads();    // vmcnt drain (stage it+1 landed) + LDS read/write fence
    }

#pragma unroll
    for (int z = 0; z < NZ; ++z) {
        if (!OUTF32 && NZ == 3 && z == 2) {
            // V: write PV A-fragment chunks directly. Chunk = ((bh*128 + sblk)*4 + dblk),
            // 256 halves; element lane*4+j = V[d=dblk*16+lm][key=sblk*16+quad*4+j].
            // acc tile already has d=lm (col) and key=quad*4+r (row): direct store.
#pragma unroll
            for (int mt = 0; mt < 4; ++mt) {
                int row = m0 + mt * 16;              // s-block base (lane part quad*4+r)
                int b = row >> 11;
                int sblk = (row & (SEQ - 1)) >> 4;   // 0..127
#pragma unroll
                for (int nt = 0; nt < 2; ++nt) {
                    int col = n0 + w * 32 + nt * 16; // + lm
                    int h = col >> 6;
                    int dblk = (col & 63) >> 4;
                    size_t chunk = ((size_t)(b * NH + h) * 128 + sblk) * 4 + dblk;
                    uint2 pk;
                    pk.x = __builtin_bit_cast(u32, __builtin_amdgcn_cvt_pkrtz(acc[z][mt][nt][0], acc[z][mt][nt][1]));
                    pk.y = __builtin_bit_cast(u32, __builtin_amdgcn_cvt_pkrtz(acc[z][mt][nt][2], acc[z][mt][nt][3]));
                    *(uint2*)&vtout[chunk * 256 + lane * 4] = pk;
                }
            }
            continue;
        }
        const bool rope = !OUTF32;                 // z in {0,1} here
        const float osc = (!OUTF32 && z == 0) ? QSCALE : 1.0f;
#pragma unroll
        for (int mt = 0; mt < 4; ++mt)
#pragma unroll
            for (int r = 0; r < 4; ++r) {
                int row = m0 + mt * 16 + quad * 4 + r;
#pragma unroll
                for (int nt = 0; nt < 2; ++nt) {
                    int col = n0 + w * 32 + nt * 16 + lm;
                    float v  = acc[z][mt][nt][r];
                    if (rope) {
                        float pv = __shfl_xor(v, 1);
                        float2 cs = ropetab[(row & (SEQ - 1)) * 32 + ((col & 63) >> 1)];
                        v = (lm & 1) ? fmaf(pv, cs.y, v * cs.x) : fmaf(v, cs.x, -pv * cs.y);
                    }
                    v *= osc;
                    if (OUTF32) {
                        outf[(size_t)row * DM + col] = v;
                    } else {
                        float hv = __shfl_xor(v, 1);
                        if (!(lm & 1)) {
                            u32 pk = (u32)f2bf(v) | ((u32)f2bf(hv) << 16);
                            *(u32*)&outbf[(size_t)z * ((size_t)MM * DM) + (size_t)row * DM + col] = pk;
                        }
                    }
                }
            }
    }
}

// ---------------- causal flash attention, fragment-linear LDS, k-tile 64 ------------
// q-tile 128, 4 waves x 32 q-rows (2 q-fragments/wave); k-tile 64, double-buffered.
// ALL LDS accesses are fragment-linear (chunk_base + lane*16B/8B): zero bank
// conflicts, zero per-read address VALU. K is gathered fragment-wise from natural
// layout via per-lane global addresses (global_load_lds: global side is per-lane,
// LDS side linear). V arrives pre-fragmented from the QKV GEMM. Row-sum (lsum) is
// computed on the matrix pipe via a ones-fragment MFMA (o5), not VALU fmacs.
// Epilogue writes AO in shuffled-fragment layout for the Wo GEMM.
__global__ __launch_bounds__(256, 4) void attn_kernel(const u16* __restrict__ Q,
                                                      const u16* __restrict__ K,
                                                      const _Float16* __restrict__ Vf,
                                                      u16* __restrict__ AO) {
    const int u  = blockIdx.x;
    const int qt = (u < 256) ? (15 - (u >> 5)) : ((u >> 5) - 8);
    const int bh = u & 31;
    const int b  = bh >> 4, h = bh & 15;
    const int q0 = qt * 128;
    const int tid = threadIdx.x, w = tid >> 6, lane = tid & 63;
    const int lm = lane & 15, quad = lane >> 4;

    __shared__ __align__(16) u16      lsK[2][8 * 512];    // 2 x 8KB: 8 K-frag chunks
    __shared__ __align__(16) _Float16 lsV[2][16 * 256];   // 2 x 8KB: 16 V-frag chunks

    bf16x8 qb[2][2];              // [qi][ks]; wave w owns q-rows w*32 .. w*32+31
#pragma unroll
    for (int qi = 0; qi < 2; ++qi)
#pragma unroll
        for (int ks = 0; ks < 2; ++ks)
            qb[qi][ks] = *(const bf16x8*)
                &Q[(size_t)(b * SEQ + q0 + w * 32 + qi * 16 + lm) * DM + h * DH + ks * 32 + quad * 8];

    const floatx4 z4 = {0.f, 0.f, 0.f, 0.f};
    floatx4 o[2][4];              // O^T[d][q]: d = dt*16+quad*4+r, q = lm
    floatx4 o5[2];                // row-sum accumulator (ones-row MFMA)
#pragma unroll
    for (int qi = 0; qi < 2; ++qi) {
#pragma unroll
        for (int dt = 0; dt < 4; ++dt) o[qi][dt] = z4;
        o5[qi] = z4;
    }

    // K gather base: per-lane part lm*DM + quad*8 (16B per lane, 64B/row coalesced)
    const u16* Kb = K + (size_t)(b * SEQ) * DM + h * DH + (size_t)lm * DM + quad * 8;
    // V fragment chunks: 16 contiguous chunks (8KB) per k-tile
    const _Float16* Vb = Vf + (size_t)bh * (128 * 4 * 256);

    auto stageKV = [&](int buf, int kt) {
        // K: 8 chunks (st 0..3, ks 0..1); wave w stages chunks w*2, w*2+1
#pragma unroll
        for (int j = 0; j < 2; ++j) {
            int c = w * 2 + j;
            async16(Kb + (size_t)(kt * 64 + (c >> 1) * 16) * DM + (c & 1) * 32,
                    &lsK[buf][c * 512 + lane * 8]);
        }
        // V: linear copy of 8KB (global layout == LDS layout)
#pragma unroll
        for (int p = 0; p < 2; ++p) {
            int off = p * 2048 + w * 512 + lane * 8;
            async16(Vb + (size_t)kt * 4096 + off, &lsV[buf][off]);
        }
    };

    stageKV(0, 0);
    const int nkt = 2 * qt + 2;
    const halfx4 ones = {(_Float16)1.f, (_Float16)1.f, (_Float16)1.f, (_Float16)1.f};

    for (int kt = 0; kt < nkt; ++kt) {
        __syncthreads();
        if (kt + 1 < nkt) stageKV((kt + 1) & 1, kt + 1);
        const u16*      Lk = lsK[kt & 1];
        const _Float16* Lv = lsV[kt & 1];

        // QK^T: fragment-linear ka, each read feeds both q-fragments
        floatx4 s4[2][4];
#pragma unroll
        for (int qi = 0; qi < 2; ++qi)
#pragma unroll
            for (int st = 0; st < 4; ++st) s4[qi][st] = z4;
#pragma unroll
        for (int ks = 0; ks < 2; ++ks)
#pragma unroll
            for (int st = 0; st < 4; ++st) {
                bf16x8 ka = *(const bf16x8*)&Lk[(st * 2 + ks) * 512 + lane * 8];
#pragma unroll
                for (int qi = 0; qi < 2; ++qi)
                    s4[qi][st] = __builtin_amdgcn_mfma_f32_16x16x32_bf16(ka, qb[qi][ks], s4[qi][st], 0, 0, 0);
            }

        const int rel = kt - 2 * qt;   // >= 0 only for the last two k-tiles
#pragma unroll
        for (int st = 0; st < 4; ++st) {
            halfx4 pb2[2];
#pragma unroll
            for (int qi = 0; qi < 2; ++qi) {
#pragma unroll
                for (int r = 0; r < 4; ++r) {
                    float v = s4[qi][st][r];
                    if (rel >= 0) {
                        int keyloc = rel * 64 + st * 16 + quad * 4 + r;
                        if (keyloc > w * 32 + qi * 16 + lm) v = -1e30f;
                    }
                    s4[qi][st][r] = exp2f(v);
                }
                uintx2 pk2;
                pk2.x = __builtin_bit_cast(u32, __builtin_amdgcn_cvt_pkrtz(s4[qi][st][0], s4[qi][st][1]));
                pk2.y = __builtin_bit_cast(u32, __builtin_amdgcn_cvt_pkrtz(s4[qi][st][2], s4[qi][st][3]));
                pb2[qi] = __builtin_bit_cast(halfx4, pk2);
            }
            // PV: fragment-linear va, feeds both q-fragments; lsum via ones-MFMA
#pragma unroll
            for (int dt = 0; dt < 4; ++dt) {
                halfx4 va = *(const halfx4*)&Lv[(st * 4 + dt) * 256 + lane * 4];
#pragma unroll
                for (int qi = 0; qi < 2; ++qi)
                    o[qi][dt] = __builtin_amdgcn_mfma_f32_16x16x16f16(va, pb2[qi], o[qi][dt], 0, 0, 0);
            }
#pragma unroll
            for (int qi = 0; qi < 2; ++qi)
                o5[qi] = __builtin_amdgcn_mfma_f32_16x16x16f16(ones, pb2[qi], o5[qi], 0, 0, 0);
        }
    }

    // o5[qi] rows are all the full row-sum for q = lm (ones-row MFMA sums all k)
    float rl[2] = {1.0f / o5[0][0], 1.0f / o5[1][0]};

    // epilogue: O^T (reg) -> LDS (swizzled natural [q][d]) -> shuffled-frag AO store
    __syncthreads();                       // all waves done with lsK/lsV
    u16* eb = (u16*)&lsK[0][0];            // 128x64 bf16 = 16 KB (spans both K buffers)
#pragma unroll
    for (int qi = 0; qi < 2; ++qi) {
        const int q = w * 32 + qi * 16 + lm;
#pragma unroll
        for (int dt = 0; dt < 4; ++dt) {
            uint2 pk;
            pk.x = (u32)f2bf(o[qi][dt][0] * rl[qi]) | ((u32)f2bf(o[qi][dt][1] * rl[qi]) << 16);
            pk.y = (u32)f2bf(o[qi][dt][2] * rl[qi]) | ((u32)f2bf(o[qi][dt][3] * rl[qi]) << 16);
            int ch = (dt * 2 + (quad >> 1)) ^ (lm & 7);
            *(uint2*)&eb[q * 64 + ch * 8 + (quad & 1) * 4] = pk;
        }
    }
    __syncthreads();
    const size_t rowblk0 = (size_t)((b * SEQ + q0) >> 4);
#pragma unroll
    for (int rbi = 0; rbi < 2; ++rbi) {
#pragma unroll
        for (int kt = 0; kt < 2; ++kt) {
            uint4 v = *(const uint4*)&eb[((w * 2 + rbi) * 16 + lm) * 64 + ((kt * 4 + quad) ^ (lm & 7)) * 8];
            *(uint4*)&AO[((rowblk0 + w * 2 + rbi) * 32 + (h * 2 + kt)) * 512 + lane * 8] = v;
        }
    }
}

extern "C" void kernel_launch(void* const* d_in, const int* in_sizes, int n_in,
                              void* d_out, int out_size, void* d_ws, size_t ws_size,
                              hipStream_t stream) {
    const float* x   = (const float*)d_in[0];
    const int*   pos = (const int*)d_in[1];
    float* out = (float*)d_out;

    u16* ws = (u16*)d_ws;
    const size_t MD = (size_t)MM * DM;
    const size_t DD = (size_t)DM * DM;
    u16* Xsh = ws;                        // shuffled X; dead after QKV -> reused as AOsh
    u16* Wsh = ws + MD;                   // 4 shuffled weights (q,k,v,o)
    u16* Qbf = ws + MD + 4 * DD;          // natural layouts
    u16* Kbf = Qbf + MD;
    u16* VtB = Kbf + MD;                  // f16 V fragment chunks (written by QKV z==2)
    float2* ropetab = (float2*)(VtB + MD);
    _Float16* Vt = (_Float16*)VtB;
    u16* AOsh = Xsh;

    // prep: bf16 shuffled X + 4 W, RoPE table (one launch)
    prep_kernel<<<dim3(128, 16), 256, 0, stream>>>(
        x, (const float*)d_in[2], (const float*)d_in[3], (const float*)d_in[4],
        (const float*)d_in[5], Xsh, Wsh, pos, ropetab);

    // fused Q/K/V projections (z-fused: A staged once, 3x MFMA per staged byte);
    // RoPE fused on Q,K; softmax scale folded into Q; V fragment chunks written directly
    gemm_f<3, false><<<dim3(64, 8), 256, 0, stream>>>(
        Xsh, Wsh, Qbf, nullptr, Vt, ropetab);

    // causal flash attention (writes AO in shuffled-frag layout)
    attn_kernel<<<dim3(512), 256, 0, stream>>>(Qbf, Kbf, Vt, AOsh);

    // output projection -> fp32 d_out
    gemm_f<1, true><<<dim3(64, 8), 256, 0, stream>>>(
        AOsh, Wsh + 3 * DD, nullptr, out, nullptr, ropetab);
}

// Round 5
// 185.887 us; speedup vs baseline: 1.1134x; 1.1134x over previous
//
#include <hip/hip_runtime.h>
#include <math.h>

typedef unsigned short u16;
typedef unsigned int   u32;
typedef __attribute__((ext_vector_type(8))) short bf16x8;
typedef __attribute__((ext_vector_type(4))) float floatx4;
typedef __attribute__((ext_vector_type(4))) _Float16 halfx4;
typedef __attribute__((ext_vector_type(2))) unsigned int uintx2;

// B=2, S=2048, D=1024, H=16, Dh=64, M=B*S=4096
#define SEQ 2048
#define DM  1024
#define NH  16
#define DH  64
#define MM  4096
#define QSCALE 0.18033688011112042f   // 0.125 * log2(e), folded into Q

__device__ __forceinline__ u16 f2bf(float f) {
    u32 u = __builtin_bit_cast(u32, f);
    u += 0x7fffu + ((u >> 16) & 1u);
    return (u16)(u >> 16);
}

__device__ __forceinline__ void async16(const void* g, void* l) {
    __builtin_amdgcn_global_load_lds(
        (const __attribute__((address_space(1))) void*)g,
        (__attribute__((address_space(3))) void*)l, 16, 0, 0);
}

// ---------------- prep: fp32 -> bf16 shuffled layout + RoPE table -------------------
// Shuffled layout: tile (rowblk=row/16, ktile=col/32); element [m=lm][k=quad*8+j]
// stored flat at (rowblk*32 + ktile)*512 + lane*8 + j. One dwordx4/lane per fragment.
// First 256 linear blocks additionally fill the RoPE table (2048x32 float2).
__global__ __launch_bounds__(256) void prep_kernel(const float* __restrict__ x,
                                                   const float* __restrict__ w0,
                                                   const float* __restrict__ w1,
                                                   const float* __restrict__ w2,
                                                   const float* __restrict__ w3,
                                                   u16* __restrict__ Xsh,
                                                   u16* __restrict__ Wsh,
                                                   const int* __restrict__ pos,
                                                   float2* __restrict__ tab) {
    const int bid = blockIdx.x, cb = blockIdx.y, tid = threadIdx.x;

    // RoPE table side-job
    int lin = bid * 16 + cb;
    if (lin < 256) {
        int i = lin * 256 + tid;       // 65536 = 2048*32
        int p = i >> 5, d2 = i & 31;
        float freq = __expf(-(float)d2 * (9.2103403719761836f / 32.0f));
        float sv, cv;
        sincosf((float)pos[p] * freq, &sv, &cv);
        tab[i] = make_float2(cv, sv);
    }

    const float* src; u16* dst; int row0;
    if (bid < 64) { src = x; dst = Xsh; row0 = bid * 64; }
    else {
        int wi = (bid - 64) >> 4;
        src = (wi == 0) ? w0 : (wi == 1) ? w1 : (wi == 2) ? w2 : w3;
        dst = Wsh + (size_t)wi * DM * DM;
        row0 = ((bid - 64) & 15) * 64;
    }
    __shared__ __align__(16) u16 t[64 * 64];   // 8-elem chunks XOR-swizzled by row&7
#pragma unroll
    for (int rep = 0; rep < 4; ++rep) {
        int f = rep * 256 + tid;
        int r = f >> 4, c4 = f & 15;
        float4 v = *(const float4*)&src[(size_t)(row0 + r) * DM + cb * 64 + c4 * 4];
        uint2 pk;
        pk.x = (u32)f2bf(v.x) | ((u32)f2bf(v.y) << 16);
        pk.y = (u32)f2bf(v.z) | ((u32)f2bf(v.w) << 16);
        int ch = (c4 >> 1) ^ (r & 7);
        *(uint2*)&t[r * 64 + ch * 8 + (c4 & 1) * 4] = pk;
    }
    __syncthreads();
#pragma unroll
    for (int rep = 0; rep < 2; ++rep) {
        int s = rep * 256 + tid;
        int tile = s >> 6, l = s & 63;
        int mt = tile >> 1, kt = tile & 1, lm = l & 15, quad = l >> 4;
        int m = mt * 16 + lm;
        uint4 v = *(const uint4*)&t[m * 64 + ((kt * 4 + quad) ^ (m & 7)) * 8];
        size_t rowblk = (size_t)(row0 >> 4) + mt;
        size_t ktile  = cb * 2 + kt;
        *(uint4*)&dst[(rowblk * 32 + ktile) * 512 + l * 8] = v;
    }
}

// ---------------- fused-z NT GEMM, LDS double-buffered, stage-ahead -----------------
// C_z[M,1024] = A * W_z^T for z in [0,NZ). Block tile 64 rows x 128 cols, 4 waves,
// wave w owns cols [n0+w*32, +32). BK=32 (1 ktile/step), 32 K-steps.
// Both operands staged via global_load_lds into DOUBLE-buffered LDS; stage for step
// it+1 is issued BEFORE computing step it, so the vmcnt drain at the (single)
// end-of-iter barrier lands after 24 (NZ=3) MFMAs of latency hiding.
// A is loaded once per block (shared by 4 waves); with NZ=3 each staged byte feeds
// 3x the MFMAs (Q,K,V share A). Epilogues: z==0 Q (RoPE+QSCALE, natural bf16);
// z==1 K (RoPE, then LDS-bounce transpose -> QK-A-fragment chunks in global);
// z==2 V (PV-A-fragment chunks, direct store); OUTF32 (Wo) writes fp32.
template<int NZ, bool OUTF32>
__global__ __launch_bounds__(256, 2) void gemm_f(const u16* __restrict__ Ash,
                                                 const u16* __restrict__ Wbase,
                                                 u16* __restrict__ outbf,
                                                 float* __restrict__ outf,
                                                 _Float16* __restrict__ vtout,
                                                 u16* __restrict__ koutbf,
                                                 const float2* __restrict__ ropetab) {
    const int m0 = blockIdx.x * 64, n0 = blockIdx.y * 128;
    const int tid = threadIdx.x, lane = tid & 63, w = tid >> 6;
    const int lm = lane & 15, quad = lane >> 4;
    const int rb0 = m0 >> 4;        // 4 rowblks per block
    const int cb0 = n0 >> 4;        // 8 colblks per block

    __shared__ __align__(16) u16 lsA[2][4 * 512];        // 2 x 4KB
    __shared__ __align__(16) u16 lsB[2][NZ * 8 * 512];   // 2 x NZ*8KB

    // per-wave staging sources (chunk stride between ktiles = 512 elems)
    const u16* aSrc = Ash + ((size_t)(rb0 + w) * 32) * 512 + lane * 8;
    constexpr int NPW = NZ * 2;     // B pieces per wave (NZ*8 pieces / 4 waves)
    const u16* bSrc[NPW];
#pragma unroll
    for (int j = 0; j < NPW; ++j) {
        int p = w * NPW + j, z = p >> 3, cb8 = p & 7;
        bSrc[j] = Wbase + (size_t)z * (DM * DM)
                + ((size_t)(cb0 + cb8) * 32) * 512 + lane * 8;
    }

    auto stage = [&](int buf, int it) {
        async16(aSrc + (size_t)it * 512, &lsA[buf][w * 512 + lane * 8]);
#pragma unroll
        for (int j = 0; j < NPW; ++j)
            async16(bSrc[j] + (size_t)it * 512,
                    &lsB[buf][(w * NPW + j) * 512 + lane * 8]);
    };

    floatx4 acc[NZ][4][2];
    const floatx4 z4 = {0.f, 0.f, 0.f, 0.f};
#pragma unroll
    for (int z = 0; z < NZ; ++z)
#pragma unroll
        for (int mt = 0; mt < 4; ++mt)
#pragma unroll
            for (int nt = 0; nt < 2; ++nt) acc[z][mt][nt] = z4;

    stage(0, 0);
    __syncthreads();

#pragma unroll 2
    for (int it = 0; it < 32; ++it) {
        if (it < 31) stage((it + 1) & 1, it + 1);   // stage-ahead (hidden under MFMAs)
        const u16* La = &lsA[it & 1][0];
        const u16* Lb = &lsB[it & 1][0];
        bf16x8 a[4], b[NZ][2];
#pragma unroll
        for (int mt = 0; mt < 4; ++mt)
            a[mt] = *(const bf16x8*)&La[mt * 512 + lane * 8];
#pragma unroll
        for (int z = 0; z < NZ; ++z)
#pragma unroll
            for (int nt = 0; nt < 2; ++nt)
                b[z][nt] = *(const bf16x8*)&Lb[(z * 8 + w * 2 + nt) * 512 + lane * 8];
#pragma unroll
        for (int z = 0; z < NZ; ++z)
#pragma unroll
            for (int mt = 0; mt < 4; ++mt)
#pragma unroll
                for (int nt = 0; nt < 2; ++nt)
                    acc[z][mt][nt] = __builtin_amdgcn_mfma_f32_16x16x32_bf16(
                        a[mt], b[z][nt], acc[z][mt][nt], 0, 0, 0);
        __syncthreads();    // vmcnt drain (stage it+1 landed) + LDS read/write fence
    }

#pragma unroll
    for (int z = 0; z < NZ; ++z) {
        if (!OUTF32 && NZ == 3 && z == 2) {
            // V: write PV A-fragment chunks directly. Chunk = ((bh*128 + sblk)*4 + dblk),
            // 256 halves; element lane*4+j = V[d=dblk*16+lm][key=sblk*16+quad*4+j].
            // acc tile already has d=lm (col) and key=quad*4+r (row): direct store.
#pragma unroll
            for (int mt = 0; mt < 4; ++mt) {
                int row = m0 + mt * 16;              // s-block base (lane part quad*4+r)
                int b = row >> 11;
                int sblk = (row & (SEQ - 1)) >> 4;   // 0..127
#pragma unroll
                for (int nt = 0; nt < 2; ++nt) {
                    int col = n0 + w * 32 + nt * 16; // + lm
                    int h = col >> 6;
                    int dblk = (col & 63) >> 4;
                    size_t chunk = ((size_t)(b * NH + h) * 128 + sblk) * 4 + dblk;
                    uint2 pk;
                    pk.x = __builtin_bit_cast(u32, __builtin_amdgcn_cvt_pkrtz(acc[z][mt][nt][0], acc[z][mt][nt][1]));
                    pk.y = __builtin_bit_cast(u32, __builtin_amdgcn_cvt_pkrtz(acc[z][mt][nt][2], acc[z][mt][nt][3]));
                    *(uint2*)&vtout[chunk * 256 + lane * 4] = pk;
                }
            }
            continue;
        }
        if (!OUTF32 && NZ == 3 && z == 1) {
            // K: RoPE, then LDS-bounce transpose into QK A-fragment chunks.
            // Chunk = ((bh*128 + sblk)*2 + ks2), 512 bf16;
            // element lane*8+j = K[key=sblk*16+lm][kd=ks2*32+quad*8+j].
            u16* t = (u16*)&lsB[0][0];   // 64 x 136 u16 scratch (17.4KB of 48KB)
#pragma unroll
            for (int mt = 0; mt < 4; ++mt)
#pragma unroll
                for (int r = 0; r < 4; ++r) {
                    int row = m0 + mt * 16 + quad * 4 + r;
#pragma unroll
                    for (int nt = 0; nt < 2; ++nt) {
                        int col = n0 + w * 32 + nt * 16 + lm;
                        float v  = acc[z][mt][nt][r];
                        float pv = __shfl_xor(v, 1);
                        float2 cs = ropetab[(row & (SEQ - 1)) * 32 + ((col & 63) >> 1)];
                        v = (lm & 1) ? fmaf(pv, cs.y, v * cs.x) : fmaf(v, cs.x, -pv * cs.y);
                        t[(mt * 16 + quad * 4 + r) * 136 + (w * 32 + nt * 16 + lm)] = f2bf(v);
                    }
                }
            __syncthreads();
            {
                int bb = m0 >> 11;
                int sblk0 = (m0 & (SEQ - 1)) >> 4;
                int h0 = n0 >> 6;
#pragma unroll
                for (int j = 0; j < 4; ++j) {
                    int c = w * 4 + j;          // hloc(1b) | sblkl(2b) | ks2(1b)
                    int hloc = c >> 3, sblkl = (c >> 1) & 3, ks2 = c & 1;
                    uint4 v = *(const uint4*)&t[(sblkl * 16 + lm) * 136 + hloc * 64 + ks2 * 32 + quad * 8];
                    size_t chunk = ((size_t)(bb * NH + h0 + hloc) * 128 + sblk0 + sblkl) * 2 + ks2;
                    *(uint4*)&koutbf[chunk * 512 + lane * 8] = v;
                }
            }
            continue;
        }
        const bool rope = !OUTF32;                 // only z==0 reaches here when NZ==3
        const float osc = (!OUTF32 && z == 0) ? QSCALE : 1.0f;
#pragma unroll
        for (int mt = 0; mt < 4; ++mt)
#pragma unroll
            for (int r = 0; r < 4; ++r) {
                int row = m0 + mt * 16 + quad * 4 + r;
#pragma unroll
                for (int nt = 0; nt < 2; ++nt) {
                    int col = n0 + w * 32 + nt * 16 + lm;
                    float v  = acc[z][mt][nt][r];
                    if (rope) {
                        float pv = __shfl_xor(v, 1);
                        float2 cs = ropetab[(row & (SEQ - 1)) * 32 + ((col & 63) >> 1)];
                        v = (lm & 1) ? fmaf(pv, cs.y, v * cs.x) : fmaf(v, cs.x, -pv * cs.y);
                    }
                    v *= osc;
                    if (OUTF32) {
                        outf[(size_t)row * DM + col] = v;
                    } else {
                        float hv = __shfl_xor(v, 1);
                        if (!(lm & 1)) {
                            u32 pk = (u32)f2bf(v) | ((u32)f2bf(hv) << 16);
                            *(u32*)&outbf[(size_t)z * ((size_t)MM * DM) + (size_t)row * DM + col] = pk;
                        }
                    }
                }
            }
    }
}

// ---------------- causal flash attention, fragment-linear LDS, k-tile 128 -----------
// q-tile 128, 4 waves x 32 q-rows (2 q-fragments/wave); k-tile 128, double-buffered,
// ONE barrier per k-tile. ALL LDS accesses are fragment-linear (chunk + lane*16B/8B):
// zero bank conflicts, zero per-read address VALU. K and V both arrive PRE-FRAGMENTED
// from the QKV GEMM, so staging is a pure linear coalesced copy (8 async16/wave/tile).
// Row-sum rides the matrix pipe via a ones-fragment MFMA (o5).
// Epilogue writes AO in shuffled-fragment layout for the Wo GEMM.
__global__ __launch_bounds__(256, 2) void attn_kernel(const u16* __restrict__ Q,
                                                      const u16* __restrict__ Kf,
                                                      const _Float16* __restrict__ Vf,
                                                      u16* __restrict__ AO) {
    const int u  = blockIdx.x;
    const int qt = (u < 256) ? (15 - (u >> 5)) : ((u >> 5) - 8);
    const int bh = u & 31;
    const int b  = bh >> 4, h = bh & 15;
    const int q0 = qt * 128;
    const int tid = threadIdx.x, w = tid >> 6, lane = tid & 63;
    const int lm = lane & 15, quad = lane >> 4;

    __shared__ __align__(16) u16      lsK[2][16 * 512];   // 2 x 16KB: 16 K-frag chunks
    __shared__ __align__(16) _Float16 lsV[2][32 * 256];   // 2 x 16KB: 32 V-frag chunks

    bf16x8 qb[2][2];              // [qi][ks]; wave w owns q-rows w*32 .. w*32+31
#pragma unroll
    for (int qi = 0; qi < 2; ++qi)
#pragma unroll
        for (int ks = 0; ks < 2; ++ks)
            qb[qi][ks] = *(const bf16x8*)
                &Q[(size_t)(b * SEQ + q0 + w * 32 + qi * 16 + lm) * DM + h * DH + ks * 32 + quad * 8];

    const floatx4 z4 = {0.f, 0.f, 0.f, 0.f};
    floatx4 o[2][4];              // O^T[d][q]: d = dt*16+quad*4+r, q = lm
    floatx4 o5[2];                // row-sum accumulator (ones-row MFMA)
#pragma unroll
    for (int qi = 0; qi < 2; ++qi) {
#pragma unroll
        for (int dt = 0; dt < 4; ++dt) o[qi][dt] = z4;
        o5[qi] = z4;
    }

    // pre-fragmented K: 256 chunks/bh (1KB each); k-tile kt = chunks [kt*16, +16)
    const u16*      Kb = Kf + (size_t)bh * (256 * 512);
    // pre-fragmented V: 512 chunks/bh (512B each); k-tile kt = chunks [kt*32, +32)
    const _Float16* Vb = Vf + (size_t)bh * (128 * 4 * 256);

    auto stageKV = [&](int buf, int kt) {
#pragma unroll
        for (int j = 0; j < 4; ++j) {
            // K: 16KB linear (wave w copies chunks w*4..w*4+3)
            int kc = w * 4 + j;
            async16(Kb + ((size_t)kt * 16 + kc) * 512 + lane * 8,
                    &lsK[buf][kc * 512 + lane * 8]);
            // V: 16KB linear (wave w copies quarter w, 1KB per async16)
            int off = w * 2048 + j * 512 + lane * 8;
            async16(Vb + (size_t)kt * 8192 + off, &lsV[buf][off]);
        }
    };

    stageKV(0, 0);
    const halfx4 ones = {(_Float16)1.f, (_Float16)1.f, (_Float16)1.f, (_Float16)1.f};

    for (int kt = 0; kt <= qt; ++kt) {
        __syncthreads();
        if (kt < qt) stageKV((kt + 1) & 1, kt + 1);
        const u16*      Lk = lsK[kt & 1];
        const _Float16* Lv = lsV[kt & 1];

        // QK^T: fragment-linear ka, each read feeds both q-fragments
        floatx4 s4[2][8];
#pragma unroll
        for (int qi = 0; qi < 2; ++qi)
#pragma unroll
            for (int st = 0; st < 8; ++st) s4[qi][st] = z4;
#pragma unroll
        for (int ks = 0; ks < 2; ++ks)
#pragma unroll
            for (int st = 0; st < 8; ++st) {
                bf16x8 ka = *(const bf16x8*)&Lk[(st * 2 + ks) * 512 + lane * 8];
#pragma unroll
                for (int qi = 0; qi < 2; ++qi)
                    s4[qi][st] = __builtin_amdgcn_mfma_f32_16x16x32_bf16(ka, qb[qi][ks], s4[qi][st], 0, 0, 0);
            }

        const bool diag = (kt == qt);
#pragma unroll
        for (int st = 0; st < 8; ++st) {
            halfx4 pb2[2];
#pragma unroll
            for (int qi = 0; qi < 2; ++qi) {
#pragma unroll
                for (int r = 0; r < 4; ++r) {
                    float v = s4[qi][st][r];
                    if (diag) {
                        int keyloc = st * 16 + quad * 4 + r;
                        if (keyloc > w * 32 + qi * 16 + lm) v = -1e30f;
                    }
                    s4[qi][st][r] = exp2f(v);
                }
                uintx2 pk2;
                pk2.x = __builtin_bit_cast(u32, __builtin_amdgcn_cvt_pkrtz(s4[qi][st][0], s4[qi][st][1]));
                pk2.y = __builtin_bit_cast(u32, __builtin_amdgcn_cvt_pkrtz(s4[qi][st][2], s4[qi][st][3]));
                pb2[qi] = __builtin_bit_cast(halfx4, pk2);
            }
            // PV: fragment-linear va, feeds both q-fragments; lsum via ones-MFMA
#pragma unroll
            for (int dt = 0; dt < 4; ++dt) {
                halfx4 va = *(const halfx4*)&Lv[(st * 4 + dt) * 256 + lane * 4];
#pragma unroll
                for (int qi = 0; qi < 2; ++qi)
                    o[qi][dt] = __builtin_amdgcn_mfma_f32_16x16x16f16(va, pb2[qi], o[qi][dt], 0, 0, 0);
            }
#pragma unroll
            for (int qi = 0; qi < 2; ++qi)
                o5[qi] = __builtin_amdgcn_mfma_f32_16x16x16f16(ones, pb2[qi], o5[qi], 0, 0, 0);
        }
    }

    // o5[qi] rows all hold the full row-sum for q = lm (ones-row MFMA sums all keys)
    float rl[2] = {1.0f / o5[0][0], 1.0f / o5[1][0]};

    // epilogue: O^T (reg) -> LDS (swizzled natural [q][d]) -> shuffled-frag AO store
    __syncthreads();                       // all waves done with lsK/lsV
    u16* eb = (u16*)&lsK[0][0];            // 128x64 bf16 = 16 KB (= lsK buffer 0)
#pragma unroll
    for (int qi = 0; qi < 2; ++qi) {
        const int q = w * 32 + qi * 16 + lm;
#pragma unroll
        for (int dt = 0; dt < 4; ++dt) {
            uint2 pk;
            pk.x = (u32)f2bf(o[qi][dt][0] * rl[qi]) | ((u32)f2bf(o[qi][dt][1] * rl[qi]) << 16);
            pk.y = (u32)f2bf(o[qi][dt][2] * rl[qi]) | ((u32)f2bf(o[qi][dt][3] * rl[qi]) << 16);
            int ch = (dt * 2 + (quad >> 1)) ^ (lm & 7);
            *(uint2*)&eb[q * 64 + ch * 8 + (quad & 1) * 4] = pk;
        }
    }
    __syncthreads();
    const size_t rowblk0 = (size_t)((b * SEQ + q0) >> 4);
#pragma unroll
    for (int rbi = 0; rbi < 2; ++rbi) {
#pragma unroll
        for (int kt = 0; kt < 2; ++kt) {
            uint4 v = *(const uint4*)&eb[((w * 2 + rbi) * 16 + lm) * 64 + ((kt * 4 + quad) ^ (lm & 7)) * 8];
            *(uint4*)&AO[((rowblk0 + w * 2 + rbi) * 32 + (h * 2 + kt)) * 512 + lane * 8] = v;
        }
    }
}

extern "C" void kernel_launch(void* const* d_in, const int* in_sizes, int n_in,
                              void* d_out, int out_size, void* d_ws, size_t ws_size,
                              hipStream_t stream) {
    const float* x   = (const float*)d_in[0];
    const int*   pos = (const int*)d_in[1];
    float* out = (float*)d_out;

    u16* ws = (u16*)d_ws;
    const size_t MD = (size_t)MM * DM;
    const size_t DD = (size_t)DM * DM;
    u16* Xsh = ws;                        // shuffled X; dead after QKV -> reused as AOsh
    u16* Wsh = ws + MD;                   // 4 shuffled weights (q,k,v,o)
    u16* Qbf = ws + MD + 4 * DD;          // Q natural bf16
    u16* Kfb = Qbf + MD;                  // K as QK-A-fragment chunks
    u16* VtB = Kfb + MD;                  // f16 V as PV-A-fragment chunks
    float2* ropetab = (float2*)(VtB + MD);
    _Float16* Vt = (_Float16*)VtB;
    u16* AOsh = Xsh;

    // prep: bf16 shuffled X + 4 W, RoPE table (one launch)
    prep_kernel<<<dim3(128, 16), 256, 0, stream>>>(
        x, (const float*)d_in[2], (const float*)d_in[3], (const float*)d_in[4],
        (const float*)d_in[5], Xsh, Wsh, pos, ropetab);

    // fused Q/K/V projections (z-fused: A staged once, 3x MFMA per staged byte);
    // RoPE fused on Q,K; softmax scale folded into Q; K and V written pre-fragmented
    gemm_f<3, false><<<dim3(64, 8), 256, 0, stream>>>(
        Xsh, Wsh, Qbf, nullptr, Vt, Kfb, ropetab);

    // causal flash attention (writes AO in shuffled-frag layout)
    attn_kernel<<<dim3(512), 256, 0, stream>>>(Qbf, Kfb, Vt, AOsh);

    // output projection -> fp32 d_out
    gemm_f<1, true><<<dim3(64, 8), 256, 0, stream>>>(
        AOsh, Wsh + 3 * DD, nullptr, out, nullptr, nullptr, ropetab);
}

// Round 6
// 179.507 us; speedup vs baseline: 1.1530x; 1.0355x over previous
//
#include <hip/hip_runtime.h>
#include <math.h>

typedef unsigned short u16;
typedef unsigned int   u32;
typedef __attribute__((ext_vector_type(8))) short bf16x8;
typedef __attribute__((ext_vector_type(4))) float floatx4;
typedef __attribute__((ext_vector_type(4))) _Float16 halfx4;
typedef __attribute__((ext_vector_type(2))) unsigned int uintx2;

// B=2, S=2048, D=1024, H=16, Dh=64, M=B*S=4096
#define SEQ 2048
#define DM  1024
#define NH  16
#define DH  64
#define MM  4096
#define QSCALE 0.18033688011112042f   // 0.125 * log2(e), folded into Q

__device__ __forceinline__ u16 f2bf(float f) {
    u32 u = __builtin_bit_cast(u32, f);
    u += 0x7fffu + ((u >> 16) & 1u);
    return (u16)(u >> 16);
}

__device__ __forceinline__ void async16(const void* g, void* l) {
    __builtin_amdgcn_global_load_lds(
        (const __attribute__((address_space(1))) void*)g,
        (__attribute__((address_space(3))) void*)l, 16, 0, 0);
}

// ---------------- prep: fp32 -> bf16 shuffled layout + RoPE table -------------------
// Shuffled layout: tile (rowblk=row/16, ktile=col/32); element [m=lm][k=quad*8+j]
// stored flat at (rowblk*32 + ktile)*512 + lane*8 + j. One dwordx4/lane per fragment.
// First 256 linear blocks additionally fill the RoPE table (2048x32 float2).
__global__ __launch_bounds__(256) void prep_kernel(const float* __restrict__ x,
                                                   const float* __restrict__ w0,
                                                   const float* __restrict__ w1,
                                                   const float* __restrict__ w2,
                                                   const float* __restrict__ w3,
                                                   u16* __restrict__ Xsh,
                                                   u16* __restrict__ Wsh,
                                                   const int* __restrict__ pos,
                                                   float2* __restrict__ tab) {
    const int bid = blockIdx.x, cb = blockIdx.y, tid = threadIdx.x;

    // RoPE table side-job
    int lin = bid * 16 + cb;
    if (lin < 256) {
        int i = lin * 256 + tid;       // 65536 = 2048*32
        int p = i >> 5, d2 = i & 31;
        float freq = __expf(-(float)d2 * (9.2103403719761836f / 32.0f));
        float sv, cv;
        sincosf((float)pos[p] * freq, &sv, &cv);
        tab[i] = make_float2(cv, sv);
    }

    const float* src; u16* dst; int row0;
    if (bid < 64) { src = x; dst = Xsh; row0 = bid * 64; }
    else {
        int wi = (bid - 64) >> 4;
        src = (wi == 0) ? w0 : (wi == 1) ? w1 : (wi == 2) ? w2 : w3;
        dst = Wsh + (size_t)wi * DM * DM;
        row0 = ((bid - 64) & 15) * 64;
    }
    __shared__ __align__(16) u16 t[64 * 64];   // 8-elem chunks XOR-swizzled by row&7
#pragma unroll
    for (int rep = 0; rep < 4; ++rep) {
        int f = rep * 256 + tid;
        int r = f >> 4, c4 = f & 15;
        float4 v = *(const float4*)&src[(size_t)(row0 + r) * DM + cb * 64 + c4 * 4];
        uint2 pk;
        pk.x = (u32)f2bf(v.x) | ((u32)f2bf(v.y) << 16);
        pk.y = (u32)f2bf(v.z) | ((u32)f2bf(v.w) << 16);
        int ch = (c4 >> 1) ^ (r & 7);
        *(uint2*)&t[r * 64 + ch * 8 + (c4 & 1) * 4] = pk;
    }
    __syncthreads();
#pragma unroll
    for (int rep = 0; rep < 2; ++rep) {
        int s = rep * 256 + tid;
        int tile = s >> 6, l = s & 63;
        int mt = tile >> 1, kt = tile & 1, lm = l & 15, quad = l >> 4;
        int m = mt * 16 + lm;
        uint4 v = *(const uint4*)&t[m * 64 + ((kt * 4 + quad) ^ (m & 7)) * 8];
        size_t rowblk = (size_t)(row0 >> 4) + mt;
        size_t ktile  = cb * 2 + kt;
        *(uint4*)&dst[(rowblk * 32 + ktile) * 512 + l * 8] = v;
    }
}

// ---------------- per-z NT GEMM, 128x128 tile, LDS double-buffered, stage-ahead -----
// C_z[M,1024] = A * W_z^T, z = blockIdx.z. Block tile BM x 128 (BM = MREP*32),
// 4 waves (2x2), wave tile (MREP*16) x 64: m-rep MREP, n-rep 4 -> reads/iter =
// MREP+4 feeding MREP*4 MFMAs (best reuse ratio). BK=32, 32 K-steps, stage-ahead
// double-buffer (stage it+1 issued before computing it).
// QKV (MREP=4): grid 32x8x3 = 768 blocks = 3 independent blocks/CU (12 waves/CU,
// launch_bounds(256,3)) -- 1.5x the resident waves of the z-fused version, and
// blocks sharing an A panel (same bx, all by/z; linear-id stride 32 == 0 mod 8)
// land on the same XCD -> A re-reads are XCD-L2 hits.
// Epilogues: z==0 Q (RoPE+QSCALE, natural bf16); z==1 K (RoPE + LDS-bounce
// transpose -> QK-A-fragment chunks); z==2 V (PV-A-fragment chunks);
// OUTF32 (Wo, MREP=2) writes fp32.
template<int MREP, bool OUTF32>
__global__ __launch_bounds__(256, (MREP == 4) ? 3 : 2)
void gemm_s(const u16* __restrict__ Ash,
            const u16* __restrict__ Wbase,
            u16* __restrict__ qout,
            float* __restrict__ outf,
            _Float16* __restrict__ vtout,
            u16* __restrict__ kout,
            const float2* __restrict__ ropetab) {
    constexpr int BM  = MREP * 32;         // 128 (QKV) or 64 (Wo)
    constexpr int AC  = 2 * MREP;          // A chunks per K-step
    constexpr int APW = AC / 4;            // A chunks staged per wave
    constexpr int STEP = (AC + 8) * 512;   // u16 per LDS buffer
    constexpr int SHN  = (MREP == 4) ? (128 * 136) : (2 * STEP);  // K-scratch union

    const int z  = blockIdx.z;
    const u16* Wp = Wbase + (size_t)z * (DM * DM);
    const int m0 = blockIdx.x * BM, n0 = blockIdx.y * 128;
    const int tid = threadIdx.x, lane = tid & 63, w = tid >> 6;
    const int wr = w >> 1, wc = w & 1;
    const int lm = lane & 15, quad = lane >> 4;
    const int rb0 = m0 >> 4, cb0 = n0 >> 4;

    __shared__ __align__(16) u16 sh[SHN];

    auto stage = [&](int buf, int it) {
        u16* la = sh + buf * STEP;
        u16* lb = la + AC * 512;
#pragma unroll
        for (int j = 0; j < APW; ++j) {
            int c = w * APW + j;
            async16(Ash + ((size_t)(rb0 + c) * 32 + it) * 512 + lane * 8,
                    &la[c * 512 + lane * 8]);
        }
#pragma unroll
        for (int j = 0; j < 2; ++j) {
            int c = w * 2 + j;
            async16(Wp + ((size_t)(cb0 + c) * 32 + it) * 512 + lane * 8,
                    &lb[c * 512 + lane * 8]);
        }
    };

    floatx4 acc[MREP][4];
    const floatx4 z4 = {0.f, 0.f, 0.f, 0.f};
#pragma unroll
    for (int mt = 0; mt < MREP; ++mt)
#pragma unroll
        for (int nt = 0; nt < 4; ++nt) acc[mt][nt] = z4;

    stage(0, 0);
    __syncthreads();

#pragma unroll 2
    for (int it = 0; it < 32; ++it) {
        if (it < 31) stage((it + 1) & 1, it + 1);   // stage-ahead (hidden under MFMAs)
        const u16* la = sh + (it & 1) * STEP;
        const u16* lb = la + AC * 512;
        bf16x8 a[MREP], b[4];
#pragma unroll
        for (int mt = 0; mt < MREP; ++mt)
            a[mt] = *(const bf16x8*)&la[(wr * MREP + mt) * 512 + lane * 8];
#pragma unroll
        for (int nt = 0; nt < 4; ++nt)
            b[nt] = *(const bf16x8*)&lb[(wc * 4 + nt) * 512 + lane * 8];
#pragma unroll
        for (int mt = 0; mt < MREP; ++mt)
#pragma unroll
            for (int nt = 0; nt < 4; ++nt)
                acc[mt][nt] = __builtin_amdgcn_mfma_f32_16x16x32_bf16(
                    a[mt], b[nt], acc[mt][nt], 0, 0, 0);
        __syncthreads();    // vmcnt drain (stage it+1 landed) + LDS read/write fence
    }

    if constexpr (OUTF32) {
#pragma unroll
        for (int mt = 0; mt < MREP; ++mt)
#pragma unroll
            for (int r = 0; r < 4; ++r) {
                int row = m0 + wr * (MREP * 16) + mt * 16 + quad * 4 + r;
#pragma unroll
                for (int nt = 0; nt < 4; ++nt) {
                    int col = n0 + wc * 64 + nt * 16 + lm;
                    outf[(size_t)row * DM + col] = acc[mt][nt][r];
                }
            }
        return;
    } else {
        if (z == 0) {
            // Q: RoPE + QSCALE, natural bf16 (pair store via lane-parity)
#pragma unroll
            for (int mt = 0; mt < MREP; ++mt)
#pragma unroll
                for (int r = 0; r < 4; ++r) {
                    int row = m0 + wr * (MREP * 16) + mt * 16 + quad * 4 + r;
#pragma unroll
                    for (int nt = 0; nt < 4; ++nt) {
                        int col = n0 + wc * 64 + nt * 16 + lm;
                        float v  = acc[mt][nt][r];
                        float pv = __shfl_xor(v, 1);
                        float2 cs = ropetab[(row & (SEQ - 1)) * 32 + ((col & 63) >> 1)];
                        v = (lm & 1) ? fmaf(pv, cs.y, v * cs.x) : fmaf(v, cs.x, -pv * cs.y);
                        v *= QSCALE;
                        float hv = __shfl_xor(v, 1);
                        if (!(lm & 1)) {
                            u32 pk = (u32)f2bf(v) | ((u32)f2bf(hv) << 16);
                            *(u32*)&qout[(size_t)row * DM + col] = pk;
                        }
                    }
                }
        } else if (z == 1) {
            if constexpr (MREP == 4) {
                // K: RoPE, LDS-bounce transpose into QK A-fragment chunks.
                // Chunk = ((bh*128 + sblk)*2 + ks2), 512 bf16;
                // element lane*8+j = K[key=sblk*16+lm][kd=ks2*32+quad*8+j].
                u16* t = sh;   // 128 x 136 u16 scratch (union over stage buffers)
#pragma unroll
                for (int mt = 0; mt < MREP; ++mt)
#pragma unroll
                    for (int r = 0; r < 4; ++r) {
                        int rl  = wr * 64 + mt * 16 + quad * 4 + r;
                        int row = m0 + rl;
#pragma unroll
                        for (int nt = 0; nt < 4; ++nt) {
                            int cl  = wc * 64 + nt * 16 + lm;
                            int col = n0 + cl;
                            float v  = acc[mt][nt][r];
                            float pv = __shfl_xor(v, 1);
                            float2 cs = ropetab[(row & (SEQ - 1)) * 32 + ((col & 63) >> 1)];
                            v = (lm & 1) ? fmaf(pv, cs.y, v * cs.x) : fmaf(v, cs.x, -pv * cs.y);
                            t[rl * 136 + cl] = f2bf(v);
                        }
                    }
                __syncthreads();
                {
                    int bb = m0 >> 11;
                    int sblk0 = (m0 & (SEQ - 1)) >> 4;
                    int h0 = n0 >> 6;
#pragma unroll
                    for (int j = 0; j < 8; ++j) {
                        int c = w * 8 + j;          // hloc(1b) | sblkl(3b) | ks2(1b)
                        int hloc = c >> 4, sblkl = (c >> 1) & 7, ks2 = c & 1;
                        uint4 v4 = *(const uint4*)&t[(sblkl * 16 + lm) * 136 + hloc * 64 + ks2 * 32 + quad * 8];
                        size_t chunk = ((size_t)(bb * NH + h0 + hloc) * 128 + sblk0 + sblkl) * 2 + ks2;
                        *(uint4*)&kout[chunk * 512 + lane * 8] = v4;
                    }
                }
            }
        } else {
            if constexpr (MREP == 4) {
                // V: PV A-fragment chunks. Chunk = ((b*NH+h)*128 + sblk)*4 + dblk,
                // 256 halves; element lane*4+j = V[d=dblk*16+lm][key=sblk*16+quad*4+j].
#pragma unroll
                for (int mt = 0; mt < MREP; ++mt) {
                    int row = m0 + wr * 64 + mt * 16;    // + quad*4+r in lane
                    int b = row >> 11;
                    int sblk = (row & (SEQ - 1)) >> 4;
#pragma unroll
                    for (int nt = 0; nt < 4; ++nt) {
                        int col = n0 + wc * 64 + nt * 16;  // + lm in lane
                        int h = col >> 6;
                        int dblk = (col & 63) >> 4;
                        size_t chunk = ((size_t)(b * NH + h) * 128 + sblk) * 4 + dblk;
                        uint2 pk;
                        pk.x = __builtin_bit_cast(u32, __builtin_amdgcn_cvt_pkrtz(acc[mt][nt][0], acc[mt][nt][1]));
                        pk.y = __builtin_bit_cast(u32, __builtin_amdgcn_cvt_pkrtz(acc[mt][nt][2], acc[mt][nt][3]));
                        *(uint2*)&vtout[chunk * 256 + lane * 4] = pk;
                    }
                }
            }
        }
    }
}

// ---------------- causal flash attention, fragment-linear LDS, k-tile 128 -----------
// q-tile 128, 4 waves x 32 q-rows (2 q-fragments/wave); k-tile 128, double-buffered,
// ONE barrier per k-tile. ALL LDS accesses are fragment-linear (chunk + lane*16B/8B):
// zero bank conflicts, zero per-read address VALU. K and V both arrive PRE-FRAGMENTED
// from the QKV GEMM, so staging is a pure linear coalesced copy (8 async16/wave/tile).
// Row-sum rides the matrix pipe via a ones-fragment MFMA (o5).
// Epilogue writes AO in shuffled-fragment layout for the Wo GEMM.
__global__ __launch_bounds__(256, 2) void attn_kernel(const u16* __restrict__ Q,
                                                      const u16* __restrict__ Kf,
                                                      const _Float16* __restrict__ Vf,
                                                      u16* __restrict__ AO) {
    const int u  = blockIdx.x;
    const int qt = (u < 256) ? (15 - (u >> 5)) : ((u >> 5) - 8);
    const int bh = u & 31;
    const int b  = bh >> 4, h = bh & 15;
    const int q0 = qt * 128;
    const int tid = threadIdx.x, w = tid >> 6, lane = tid & 63;
    const int lm = lane & 15, quad = lane >> 4;

    __shared__ __align__(16) u16      lsK[2][16 * 512];   // 2 x 16KB: 16 K-frag chunks
    __shared__ __align__(16) _Float16 lsV[2][32 * 256];   // 2 x 16KB: 32 V-frag chunks

    bf16x8 qb[2][2];              // [qi][ks]; wave w owns q-rows w*32 .. w*32+31
#pragma unroll
    for (int qi = 0; qi < 2; ++qi)
#pragma unroll
        for (int ks = 0; ks < 2; ++ks)
            qb[qi][ks] = *(const bf16x8*)
                &Q[(size_t)(b * SEQ + q0 + w * 32 + qi * 16 + lm) * DM + h * DH + ks * 32 + quad * 8];

    const floatx4 z4 = {0.f, 0.f, 0.f, 0.f};
    floatx4 o[2][4];              // O^T[d][q]: d = dt*16+quad*4+r, q = lm
    floatx4 o5[2];                // row-sum accumulator (ones-row MFMA)
#pragma unroll
    for (int qi = 0; qi < 2; ++qi) {
#pragma unroll
        for (int dt = 0; dt < 4; ++dt) o[qi][dt] = z4;
        o5[qi] = z4;
    }

    // pre-fragmented K: 256 chunks/bh (1KB each); k-tile kt = chunks [kt*16, +16)
    const u16*      Kb = Kf + (size_t)bh * (256 * 512);
    // pre-fragmented V: 512 chunks/bh (512B each); k-tile kt = chunks [kt*32, +32)
    const _Float16* Vb = Vf + (size_t)bh * (128 * 4 * 256);

    auto stageKV = [&](int buf, int kt) {
#pragma unroll
        for (int j = 0; j < 4; ++j) {
            // K: 16KB linear (wave w copies chunks w*4..w*4+3)
            int kc = w * 4 + j;
            async16(Kb + ((size_t)kt * 16 + kc) * 512 + lane * 8,
                    &lsK[buf][kc * 512 + lane * 8]);
            // V: 16KB linear (wave w copies quarter w, 1KB per async16)
            int off = w * 2048 + j * 512 + lane * 8;
            async16(Vb + (size_t)kt * 8192 + off, &lsV[buf][off]);
        }
    };

    stageKV(0, 0);
    const halfx4 ones = {(_Float16)1.f, (_Float16)1.f, (_Float16)1.f, (_Float16)1.f};

    for (int kt = 0; kt <= qt; ++kt) {
        __syncthreads();
        if (kt < qt) stageKV((kt + 1) & 1, kt + 1);
        const u16*      Lk = lsK[kt & 1];
        const _Float16* Lv = lsV[kt & 1];

        // QK^T: fragment-linear ka, each read feeds both q-fragments
        floatx4 s4[2][8];
#pragma unroll
        for (int qi = 0; qi < 2; ++qi)
#pragma unroll
            for (int st = 0; st < 8; ++st) s4[qi][st] = z4;
#pragma unroll
        for (int ks = 0; ks < 2; ++ks)
#pragma unroll
            for (int st = 0; st < 8; ++st) {
                bf16x8 ka = *(const bf16x8*)&Lk[(st * 2 + ks) * 512 + lane * 8];
#pragma unroll
                for (int qi = 0; qi < 2; ++qi)
                    s4[qi][st] = __builtin_amdgcn_mfma_f32_16x16x32_bf16(ka, qb[qi][ks], s4[qi][st], 0, 0, 0);
            }

        const bool diag = (kt == qt);
#pragma unroll
        for (int st = 0; st < 8; ++st) {
            halfx4 pb2[2];
#pragma unroll
            for (int qi = 0; qi < 2; ++qi) {
#pragma unroll
                for (int r = 0; r < 4; ++r) {
                    float v = s4[qi][st][r];
                    if (diag) {
                        int keyloc = st * 16 + quad * 4 + r;
                        if (keyloc > w * 32 + qi * 16 + lm) v = -1e30f;
                    }
                    s4[qi][st][r] = exp2f(v);
                }
                uintx2 pk2;
                pk2.x = __builtin_bit_cast(u32, __builtin_amdgcn_cvt_pkrtz(s4[qi][st][0], s4[qi][st][1]));
                pk2.y = __builtin_bit_cast(u32, __builtin_amdgcn_cvt_pkrtz(s4[qi][st][2], s4[qi][st][3]));
                pb2[qi] = __builtin_bit_cast(halfx4, pk2);
            }
            // PV: fragment-linear va, feeds both q-fragments; lsum via ones-MFMA
#pragma unroll
            for (int dt = 0; dt < 4; ++dt) {
                halfx4 va = *(const halfx4*)&Lv[(st * 4 + dt) * 256 + lane * 4];
#pragma unroll
                for (int qi = 0; qi < 2; ++qi)
                    o[qi][dt] = __builtin_amdgcn_mfma_f32_16x16x16f16(va, pb2[qi], o[qi][dt], 0, 0, 0);
            }
#pragma unroll
            for (int qi = 0; qi < 2; ++qi)
                o5[qi] = __builtin_amdgcn_mfma_f32_16x16x16f16(ones, pb2[qi], o5[qi], 0, 0, 0);
        }
    }

    // o5[qi] rows all hold the full row-sum for q = lm (ones-row MFMA sums all keys)
    float rl[2] = {1.0f / o5[0][0], 1.0f / o5[1][0]};

    // epilogue: O^T (reg) -> LDS (swizzled natural [q][d]) -> shuffled-frag AO store
    __syncthreads();                       // all waves done with lsK/lsV
    u16* eb = (u16*)&lsK[0][0];            // 128x64 bf16 = 16 KB (= lsK buffer 0)
#pragma unroll
    for (int qi = 0; qi < 2; ++qi) {
        const int q = w * 32 + qi * 16 + lm;
#pragma unroll
        for (int dt = 0; dt < 4; ++dt) {
            uint2 pk;
            pk.x = (u32)f2bf(o[qi][dt][0] * rl[qi]) | ((u32)f2bf(o[qi][dt][1] * rl[qi]) << 16);
            pk.y = (u32)f2bf(o[qi][dt][2] * rl[qi]) | ((u32)f2bf(o[qi][dt][3] * rl[qi]) << 16);
            int ch = (dt * 2 + (quad >> 1)) ^ (lm & 7);
            *(uint2*)&eb[q * 64 + ch * 8 + (quad & 1) * 4] = pk;
        }
    }
    __syncthreads();
    const size_t rowblk0 = (size_t)((b * SEQ + q0) >> 4);
#pragma unroll
    for (int rbi = 0; rbi < 2; ++rbi) {
#pragma unroll
        for (int kt = 0; kt < 2; ++kt) {
            uint4 v = *(const uint4*)&eb[((w * 2 + rbi) * 16 + lm) * 64 + ((kt * 4 + quad) ^ (lm & 7)) * 8];
            *(uint4*)&AO[((rowblk0 + w * 2 + rbi) * 32 + (h * 2 + kt)) * 512 + lane * 8] = v;
        }
    }
}

extern "C" void kernel_launch(void* const* d_in, const int* in_sizes, int n_in,
                              void* d_out, int out_size, void* d_ws, size_t ws_size,
                              hipStream_t stream) {
    const float* x   = (const float*)d_in[0];
    const int*   pos = (const int*)d_in[1];
    float* out = (float*)d_out;

    u16* ws = (u16*)d_ws;
    const size_t MD = (size_t)MM * DM;
    const size_t DD = (size_t)DM * DM;
    u16* Xsh = ws;                        // shuffled X; dead after QKV -> reused as AOsh
    u16* Wsh = ws + MD;                   // 4 shuffled weights (q,k,v,o)
    u16* Qbf = ws + MD + 4 * DD;          // Q natural bf16
    u16* Kfb = Qbf + MD;                  // K as QK-A-fragment chunks
    u16* VtB = Kfb + MD;                  // f16 V as PV-A-fragment chunks
    float2* ropetab = (float2*)(VtB + MD);
    _Float16* Vt = (_Float16*)VtB;
    u16* AOsh = Xsh;

    // prep: bf16 shuffled X + 4 W, RoPE table (one launch)
    prep_kernel<<<dim3(128, 16), 256, 0, stream>>>(
        x, (const float*)d_in[2], (const float*)d_in[3], (const float*)d_in[4],
        (const float*)d_in[5], Xsh, Wsh, pos, ropetab);

    // Q/K/V projections, per-z blocks (z = blockIdx.z), 128x128 tiles, 3 blocks/CU;
    // RoPE fused on Q,K; softmax scale folded into Q; K and V written pre-fragmented
    gemm_s<4, false><<<dim3(32, 8, 3), 256, 0, stream>>>(
        Xsh, Wsh, Qbf, nullptr, Vt, Kfb, ropetab);

    // causal flash attention (writes AO in shuffled-frag layout)
    attn_kernel<<<dim3(512), 256, 0, stream>>>(Qbf, Kfb, Vt, AOsh);

    // output projection -> fp32 d_out (64x128 tiles, 2 blocks/CU)
    gemm_s<2, true><<<dim3(64, 8, 1), 256, 0, stream>>>(
        AOsh, Wsh + 3 * DD, nullptr, out, nullptr, nullptr, ropetab);
}

// Round 7
// 175.401 us; speedup vs baseline: 1.1800x; 1.0234x over previous
//
#include <hip/hip_runtime.h>
#include <math.h>

typedef unsigned short u16;
typedef unsigned int   u32;
typedef __attribute__((ext_vector_type(8))) short bf16x8;
typedef __attribute__((ext_vector_type(4))) float floatx4;
typedef __attribute__((ext_vector_type(4))) _Float16 halfx4;
typedef __attribute__((ext_vector_type(8))) _Float16 halfx8;
typedef __attribute__((ext_vector_type(2))) unsigned int uintx2;

// B=2, S=2048, D=1024, H=16, Dh=64, M=B*S=4096
#define SEQ 2048
#define DM  1024
#define NH  16
#define DH  64
#define MM  4096
#define QSCALE 0.18033688011112042f   // 0.125 * log2(e), folded into Q

__device__ __forceinline__ u16 f2bf(float f) {
    u32 u = __builtin_bit_cast(u32, f);
    u += 0x7fffu + ((u >> 16) & 1u);
    return (u16)(u >> 16);
}

__device__ __forceinline__ void async16(const void* g, void* l) {
    __builtin_amdgcn_global_load_lds(
        (const __attribute__((address_space(1))) void*)g,
        (__attribute__((address_space(3))) void*)l, 16, 0, 0);
}

// ---------------- prep: fp32 -> bf16 shuffled layout + RoPE table -------------------
// Shuffled layout: tile (rowblk=row/16, ktile=col/32); element [m=lm][k=quad*8+j]
// stored flat at (rowblk*32 + ktile)*512 + lane*8 + j. One dwordx4/lane per fragment.
// First 256 linear blocks additionally fill the RoPE table (2048x32 float2).
__global__ __launch_bounds__(256) void prep_kernel(const float* __restrict__ x,
                                                   const float* __restrict__ w0,
                                                   const float* __restrict__ w1,
                                                   const float* __restrict__ w2,
                                                   const float* __restrict__ w3,
                                                   u16* __restrict__ Xsh,
                                                   u16* __restrict__ Wsh,
                                                   const int* __restrict__ pos,
                                                   float2* __restrict__ tab) {
    const int bid = blockIdx.x, cb = blockIdx.y, tid = threadIdx.x;

    // RoPE table side-job
    int lin = bid * 16 + cb;
    if (lin < 256) {
        int i = lin * 256 + tid;       // 65536 = 2048*32
        int p = i >> 5, d2 = i & 31;
        float freq = __expf(-(float)d2 * (9.2103403719761836f / 32.0f));
        float sv, cv;
        sincosf((float)pos[p] * freq, &sv, &cv);
        tab[i] = make_float2(cv, sv);
    }

    const float* src; u16* dst; int row0;
    if (bid < 64) { src = x; dst = Xsh; row0 = bid * 64; }
    else {
        int wi = (bid - 64) >> 4;
        src = (wi == 0) ? w0 : (wi == 1) ? w1 : (wi == 2) ? w2 : w3;
        dst = Wsh + (size_t)wi * DM * DM;
        row0 = ((bid - 64) & 15) * 64;
    }
    __shared__ __align__(16) u16 t[64 * 64];   // 8-elem chunks XOR-swizzled by row&7
#pragma unroll
    for (int rep = 0; rep < 4; ++rep) {
        int f = rep * 256 + tid;
        int r = f >> 4, c4 = f & 15;
        float4 v = *(const float4*)&src[(size_t)(row0 + r) * DM + cb * 64 + c4 * 4];
        uint2 pk;
        pk.x = (u32)f2bf(v.x) | ((u32)f2bf(v.y) << 16);
        pk.y = (u32)f2bf(v.z) | ((u32)f2bf(v.w) << 16);
        int ch = (c4 >> 1) ^ (r & 7);
        *(uint2*)&t[r * 64 + ch * 8 + (c4 & 1) * 4] = pk;
    }
    __syncthreads();
#pragma unroll
    for (int rep = 0; rep < 2; ++rep) {
        int s = rep * 256 + tid;
        int tile = s >> 6, l = s & 63;
        int mt = tile >> 1, kt = tile & 1, lm = l & 15, quad = l >> 4;
        int m = mt * 16 + lm;
        uint4 v = *(const uint4*)&t[m * 64 + ((kt * 4 + quad) ^ (m & 7)) * 8];
        size_t rowblk = (size_t)(row0 >> 4) + mt;
        size_t ktile  = cb * 2 + kt;
        *(uint4*)&dst[(rowblk * 32 + ktile) * 512 + l * 8] = v;
    }
}

// ---------------- per-z NT GEMM, 128x128 tile, LDS double-buffered, stage-ahead -----
// C_z[M,1024] = A * W_z^T, z = blockIdx.z. Block tile BM x 128 (BM = MREP*32),
// 4 waves (2x2), wave tile (MREP*16) x 64. BK=32, 32 K-steps, stage-ahead dbuf.
// QKV (MREP=4): grid 32x8x3 = 768 blocks = 3 blocks/CU.
// Epilogues: z==0 Q (RoPE+QSCALE, natural bf16); z==1 K (RoPE + LDS-bounce
// transpose -> QK-A-fragment chunks); z==2 V (PV-A-fragment chunks);
// OUTF32 (Wo, MREP=2) writes fp32.
template<int MREP, bool OUTF32>
__global__ __launch_bounds__(256, (MREP == 4) ? 3 : 2)
void gemm_s(const u16* __restrict__ Ash,
            const u16* __restrict__ Wbase,
            u16* __restrict__ qout,
            float* __restrict__ outf,
            _Float16* __restrict__ vtout,
            u16* __restrict__ kout,
            const float2* __restrict__ ropetab) {
    constexpr int BM  = MREP * 32;         // 128 (QKV) or 64 (Wo)
    constexpr int AC  = 2 * MREP;          // A chunks per K-step
    constexpr int APW = AC / 4;            // A chunks staged per wave
    constexpr int STEP = (AC + 8) * 512;   // u16 per LDS buffer
    constexpr int SHN  = (MREP == 4) ? (128 * 136) : (2 * STEP);  // K-scratch union

    const int z  = blockIdx.z;
    const u16* Wp = Wbase + (size_t)z * (DM * DM);
    const int m0 = blockIdx.x * BM, n0 = blockIdx.y * 128;
    const int tid = threadIdx.x, lane = tid & 63, w = tid >> 6;
    const int wr = w >> 1, wc = w & 1;
    const int lm = lane & 15, quad = lane >> 4;
    const int rb0 = m0 >> 4, cb0 = n0 >> 4;

    __shared__ __align__(16) u16 sh[SHN];

    auto stage = [&](int buf, int it) {
        u16* la = sh + buf * STEP;
        u16* lb = la + AC * 512;
#pragma unroll
        for (int j = 0; j < APW; ++j) {
            int c = w * APW + j;
            async16(Ash + ((size_t)(rb0 + c) * 32 + it) * 512 + lane * 8,
                    &la[c * 512 + lane * 8]);
        }
#pragma unroll
        for (int j = 0; j < 2; ++j) {
            int c = w * 2 + j;
            async16(Wp + ((size_t)(cb0 + c) * 32 + it) * 512 + lane * 8,
                    &lb[c * 512 + lane * 8]);
        }
    };

    floatx4 acc[MREP][4];
    const floatx4 z4 = {0.f, 0.f, 0.f, 0.f};
#pragma unroll
    for (int mt = 0; mt < MREP; ++mt)
#pragma unroll
        for (int nt = 0; nt < 4; ++nt) acc[mt][nt] = z4;

    stage(0, 0);
    __syncthreads();

#pragma unroll 2
    for (int it = 0; it < 32; ++it) {
        if (it < 31) stage((it + 1) & 1, it + 1);   // stage-ahead (hidden under MFMAs)
        const u16* la = sh + (it & 1) * STEP;
        const u16* lb = la + AC * 512;
        bf16x8 a[MREP], b[4];
#pragma unroll
        for (int mt = 0; mt < MREP; ++mt)
            a[mt] = *(const bf16x8*)&la[(wr * MREP + mt) * 512 + lane * 8];
#pragma unroll
        for (int nt = 0; nt < 4; ++nt)
            b[nt] = *(const bf16x8*)&lb[(wc * 4 + nt) * 512 + lane * 8];
#pragma unroll
        for (int mt = 0; mt < MREP; ++mt)
#pragma unroll
            for (int nt = 0; nt < 4; ++nt)
                acc[mt][nt] = __builtin_amdgcn_mfma_f32_16x16x32_bf16(
                    a[mt], b[nt], acc[mt][nt], 0, 0, 0);
        __syncthreads();    // vmcnt drain (stage it+1 landed) + LDS read/write fence
    }

    if constexpr (OUTF32) {
#pragma unroll
        for (int mt = 0; mt < MREP; ++mt)
#pragma unroll
            for (int r = 0; r < 4; ++r) {
                int row = m0 + wr * (MREP * 16) + mt * 16 + quad * 4 + r;
#pragma unroll
                for (int nt = 0; nt < 4; ++nt) {
                    int col = n0 + wc * 64 + nt * 16 + lm;
                    outf[(size_t)row * DM + col] = acc[mt][nt][r];
                }
            }
        return;
    } else {
        if (z == 0) {
            // Q: RoPE + QSCALE, natural bf16 (pair store via lane-parity)
#pragma unroll
            for (int mt = 0; mt < MREP; ++mt)
#pragma unroll
                for (int r = 0; r < 4; ++r) {
                    int row = m0 + wr * (MREP * 16) + mt * 16 + quad * 4 + r;
#pragma unroll
                    for (int nt = 0; nt < 4; ++nt) {
                        int col = n0 + wc * 64 + nt * 16 + lm;
                        float v  = acc[mt][nt][r];
                        float pv = __shfl_xor(v, 1);
                        float2 cs = ropetab[(row & (SEQ - 1)) * 32 + ((col & 63) >> 1)];
                        v = (lm & 1) ? fmaf(pv, cs.y, v * cs.x) : fmaf(v, cs.x, -pv * cs.y);
                        v *= QSCALE;
                        float hv = __shfl_xor(v, 1);
                        if (!(lm & 1)) {
                            u32 pk = (u32)f2bf(v) | ((u32)f2bf(hv) << 16);
                            *(u32*)&qout[(size_t)row * DM + col] = pk;
                        }
                    }
                }
        } else if (z == 1) {
            if constexpr (MREP == 4) {
                // K: RoPE, LDS-bounce transpose into QK A-fragment chunks.
                // Chunk = ((bh*128 + sblk)*2 + ks2), 512 bf16;
                // element lane*8+j = K[key=sblk*16+lm][kd=ks2*32+quad*8+j].
                u16* t = sh;   // 128 x 136 u16 scratch (union over stage buffers)
#pragma unroll
                for (int mt = 0; mt < MREP; ++mt)
#pragma unroll
                    for (int r = 0; r < 4; ++r) {
                        int rl  = wr * 64 + mt * 16 + quad * 4 + r;
                        int row = m0 + rl;
#pragma unroll
                        for (int nt = 0; nt < 4; ++nt) {
                            int cl  = wc * 64 + nt * 16 + lm;
                            int col = n0 + cl;
                            float v  = acc[mt][nt][r];
                            float pv = __shfl_xor(v, 1);
                            float2 cs = ropetab[(row & (SEQ - 1)) * 32 + ((col & 63) >> 1)];
                            v = (lm & 1) ? fmaf(pv, cs.y, v * cs.x) : fmaf(v, cs.x, -pv * cs.y);
                            t[rl * 136 + cl] = f2bf(v);
                        }
                    }
                __syncthreads();
                {
                    int bb = m0 >> 11;
                    int sblk0 = (m0 & (SEQ - 1)) >> 4;
                    int h0 = n0 >> 6;
#pragma unroll
                    for (int j = 0; j < 8; ++j) {
                        int c = w * 8 + j;          // hloc(1b) | sblkl(3b) | ks2(1b)
                        int hloc = c >> 4, sblkl = (c >> 1) & 7, ks2 = c & 1;
                        uint4 v4 = *(const uint4*)&t[(sblkl * 16 + lm) * 136 + hloc * 64 + ks2 * 32 + quad * 8];
                        size_t chunk = ((size_t)(bb * NH + h0 + hloc) * 128 + sblk0 + sblkl) * 2 + ks2;
                        *(uint4*)&kout[chunk * 512 + lane * 8] = v4;
                    }
                }
            }
        } else {
            if constexpr (MREP == 4) {
                // V: PV A-fragment chunks. Chunk = ((b*NH+h)*128 + sblk)*4 + dblk,
                // 256 halves; element lane*4+j = V[d=dblk*16+lm][key=sblk*16+quad*4+j].
#pragma unroll
                for (int mt = 0; mt < MREP; ++mt) {
                    int row = m0 + wr * 64 + mt * 16;    // + quad*4+r in lane
                    int b = row >> 11;
                    int sblk = (row & (SEQ - 1)) >> 4;
#pragma unroll
                    for (int nt = 0; nt < 4; ++nt) {
                        int col = n0 + wc * 64 + nt * 16;  // + lm in lane
                        int h = col >> 6;
                        int dblk = (col & 63) >> 4;
                        size_t chunk = ((size_t)(b * NH + h) * 128 + sblk) * 4 + dblk;
                        uint2 pk;
                        pk.x = __builtin_bit_cast(u32, __builtin_amdgcn_cvt_pkrtz(acc[mt][nt][0], acc[mt][nt][1]));
                        pk.y = __builtin_bit_cast(u32, __builtin_amdgcn_cvt_pkrtz(acc[mt][nt][2], acc[mt][nt][3]));
                        *(uint2*)&vtout[chunk * 256 + lane * 4] = pk;
                    }
                }
            }
        }
    }
}

// ---------------- causal flash attention, split-k, fragment-linear LDS --------------
// Work items per bh (21): singles qt=0..10 (full k-range), and qt=11..15 split into
// two k-range halves (flash split-k: no running max -> partials simply add).
// Item table ordered descending by iteration count for dispatch balance; grid 672.
// Block: 4 waves x 32 q-rows; k-tile 128, double-buffered, ONE barrier per k-tile.
// ALL LDS accesses fragment-linear (chunk + lane*16B/8B): zero bank conflicts, zero
// per-read address VALU. K/V arrive PRE-FRAGMENTED from the QKV GEMM (linear copy).
// exp2 via __builtin_amdgcn_exp2f (raw v_exp_f32; libm exp2f = ~15 VALU ops each).
// Row-sum rides the matrix pipe via a ones-fragment MFMA (o5).
// Singles write AO (shuffled-frag); splits write unnormalized O-partial f16 + lsum.
// itab entry: qt | k0<<4 | k1<<8 | split<<13 | part<<14
static __device__ const u16 itab[21] = {
    0x0B0A,                                  // s10 (11 iters)
    0x0A09,                                  // s9  (10)
    0x0908,                                  // s8  (9)
    0x280F, 0x708F, 0x6F7E, 0x0807,          // 15p0,15p1,14p1,s7 (8)
    0x270E, 0x270D, 0x6E7D, 0x6D6C, 0x0706,  // 14p0,13p0,13p1,12p1,s6 (7)
    0x260C, 0x260B, 0x6C6B, 0x0605,          // 12p0,11p0,11p1,s5 (6)
    0x0504, 0x0403, 0x0302, 0x0201, 0x0100   // s4..s0
};

__global__ __launch_bounds__(256, 2) void attn_kernel(const u16* __restrict__ Q,
                                                      const u16* __restrict__ Kf,
                                                      const _Float16* __restrict__ Vf,
                                                      u16* __restrict__ AO,
                                                      _Float16* __restrict__ Opart,
                                                      float* __restrict__ Lpart) {
    const int u  = blockIdx.x;
    const int e  = itab[u >> 5];
    const int bh = u & 31;
    const int qt = e & 15;
    const int k0 = (e >> 4) & 15;
    const int k1 = (e >> 8) & 31;
    const bool split = (e >> 13) & 1;
    const int part = e >> 14;
    const int b  = bh >> 4, h = bh & 15;
    const int q0 = qt * 128;
    const int tid = threadIdx.x, w = tid >> 6, lane = tid & 63;
    const int lm = lane & 15, quad = lane >> 4;

    __shared__ __align__(16) u16      lsK[2][16 * 512];   // 2 x 16KB: 16 K-frag chunks
    __shared__ __align__(16) _Float16 lsV[2][32 * 256];   // 2 x 16KB: 32 V-frag chunks

    bf16x8 qb[2][2];              // [qi][ks]; wave w owns q-rows w*32 .. w*32+31
#pragma unroll
    for (int qi = 0; qi < 2; ++qi)
#pragma unroll
        for (int ks = 0; ks < 2; ++ks)
            qb[qi][ks] = *(const bf16x8*)
                &Q[(size_t)(b * SEQ + q0 + w * 32 + qi * 16 + lm) * DM + h * DH + ks * 32 + quad * 8];

    const floatx4 z4 = {0.f, 0.f, 0.f, 0.f};
    floatx4 o[2][4];              // O^T[d][q]: d = dt*16+quad*4+r, q = lm
    floatx4 o5[2];                // row-sum accumulator (ones-row MFMA)
#pragma unroll
    for (int qi = 0; qi < 2; ++qi) {
#pragma unroll
        for (int dt = 0; dt < 4; ++dt) o[qi][dt] = z4;
        o5[qi] = z4;
    }

    // pre-fragmented K: 256 chunks/bh (1KB each); k-tile kt = chunks [kt*16, +16)
    const u16*      Kb = Kf + (size_t)bh * (256 * 512);
    // pre-fragmented V: 512 chunks/bh (512B each); k-tile kt = chunks [kt*32, +32)
    const _Float16* Vb = Vf + (size_t)bh * (128 * 4 * 256);

    auto stageKV = [&](int buf, int kt) {
#pragma unroll
        for (int j = 0; j < 4; ++j) {
            // K: 16KB linear (wave w copies chunks w*4..w*4+3)
            int kc = w * 4 + j;
            async16(Kb + ((size_t)kt * 16 + kc) * 512 + lane * 8,
                    &lsK[buf][kc * 512 + lane * 8]);
            // V: 16KB linear (wave w copies quarter w, 1KB per async16)
            int off = w * 2048 + j * 512 + lane * 8;
            async16(Vb + (size_t)kt * 8192 + off, &lsV[buf][off]);
        }
    };

    stageKV(k0 & 1, k0);
    const halfx4 ones = {(_Float16)1.f, (_Float16)1.f, (_Float16)1.f, (_Float16)1.f};

    for (int kt = k0; kt < k1; ++kt) {
        __syncthreads();
        if (kt + 1 < k1) stageKV((kt + 1) & 1, kt + 1);
        const u16*      Lk = lsK[kt & 1];
        const _Float16* Lv = lsV[kt & 1];

        // QK^T: fragment-linear ka, each read feeds both q-fragments
        floatx4 s4[2][8];
#pragma unroll
        for (int qi = 0; qi < 2; ++qi)
#pragma unroll
            for (int st = 0; st < 8; ++st) s4[qi][st] = z4;
#pragma unroll
        for (int ks = 0; ks < 2; ++ks)
#pragma unroll
            for (int st = 0; st < 8; ++st) {
                bf16x8 ka = *(const bf16x8*)&Lk[(st * 2 + ks) * 512 + lane * 8];
#pragma unroll
                for (int qi = 0; qi < 2; ++qi)
                    s4[qi][st] = __builtin_amdgcn_mfma_f32_16x16x32_bf16(ka, qb[qi][ks], s4[qi][st], 0, 0, 0);
            }

        const bool diag = (kt == qt);
#pragma unroll
        for (int st = 0; st < 8; ++st) {
            halfx4 pb2[2];
#pragma unroll
            for (int qi = 0; qi < 2; ++qi) {
#pragma unroll
                for (int r = 0; r < 4; ++r) {
                    float v = s4[qi][st][r];
                    if (diag) {
                        int keyloc = st * 16 + quad * 4 + r;
                        if (keyloc > w * 32 + qi * 16 + lm) v = -1e30f;
                    }
                    s4[qi][st][r] = __builtin_amdgcn_exp2f(v);   // raw v_exp_f32
                }
                uintx2 pk2;
                pk2.x = __builtin_bit_cast(u32, __builtin_amdgcn_cvt_pkrtz(s4[qi][st][0], s4[qi][st][1]));
                pk2.y = __builtin_bit_cast(u32, __builtin_amdgcn_cvt_pkrtz(s4[qi][st][2], s4[qi][st][3]));
                pb2[qi] = __builtin_bit_cast(halfx4, pk2);
            }
            // PV: fragment-linear va, feeds both q-fragments; lsum via ones-MFMA
#pragma unroll
            for (int dt = 0; dt < 4; ++dt) {
                halfx4 va = *(const halfx4*)&Lv[(st * 4 + dt) * 256 + lane * 4];
#pragma unroll
                for (int qi = 0; qi < 2; ++qi)
                    o[qi][dt] = __builtin_amdgcn_mfma_f32_16x16x16f16(va, pb2[qi], o[qi][dt], 0, 0, 0);
            }
#pragma unroll
            for (int qi = 0; qi < 2; ++qi)
                o5[qi] = __builtin_amdgcn_mfma_f32_16x16x16f16(ones, pb2[qi], o5[qi], 0, 0, 0);
        }
    }

    if (split) {
        // unnormalized O^T partial (f16, |o| <~ 1e4 << 65504) + lsum partial
        const int pi = (bh * 5 + (qt - 11)) * 2 + part;
        _Float16* Od = Opart + (size_t)pi * (128 * 64);
#pragma unroll
        for (int qi = 0; qi < 2; ++qi) {
            const int q = w * 32 + qi * 16 + lm;
#pragma unroll
            for (int dt = 0; dt < 4; ++dt) {
                uintx2 pk2;
                pk2.x = __builtin_bit_cast(u32, __builtin_amdgcn_cvt_pkrtz(o[qi][dt][0], o[qi][dt][1]));
                pk2.y = __builtin_bit_cast(u32, __builtin_amdgcn_cvt_pkrtz(o[qi][dt][2], o[qi][dt][3]));
                *(uintx2*)&Od[(size_t)q * 64 + dt * 16 + quad * 4] = pk2;
            }
            if (quad == 0) Lpart[pi * 128 + q] = o5[qi][0];
        }
        return;
    }

    // o5[qi] rows all hold the full row-sum for q = lm (ones-row MFMA sums all keys)
    float rl[2] = {1.0f / o5[0][0], 1.0f / o5[1][0]};

    // epilogue: O^T (reg) -> LDS (swizzled natural [q][d]) -> shuffled-frag AO store
    __syncthreads();                       // all waves done with lsK/lsV
    u16* eb = (u16*)&lsK[0][0];            // 128x64 bf16 = 16 KB (= lsK buffer 0)
#pragma unroll
    for (int qi = 0; qi < 2; ++qi) {
        const int q = w * 32 + qi * 16 + lm;
#pragma unroll
        for (int dt = 0; dt < 4; ++dt) {
            uint2 pk;
            pk.x = (u32)f2bf(o[qi][dt][0] * rl[qi]) | ((u32)f2bf(o[qi][dt][1] * rl[qi]) << 16);
            pk.y = (u32)f2bf(o[qi][dt][2] * rl[qi]) | ((u32)f2bf(o[qi][dt][3] * rl[qi]) << 16);
            int ch = (dt * 2 + (quad >> 1)) ^ (lm & 7);
            *(uint2*)&eb[q * 64 + ch * 8 + (quad & 1) * 4] = pk;
        }
    }
    __syncthreads();
    const size_t rowblk0 = (size_t)((b * SEQ + q0) >> 4);
#pragma unroll
    for (int rbi = 0; rbi < 2; ++rbi) {
#pragma unroll
        for (int kt = 0; kt < 2; ++kt) {
            uint4 v = *(const uint4*)&eb[((w * 2 + rbi) * 16 + lm) * 64 + ((kt * 4 + quad) ^ (lm & 7)) * 8];
            *(uint4*)&AO[((rowblk0 + w * 2 + rbi) * 32 + (h * 2 + kt)) * 512 + lane * 8] = v;
        }
    }
}

// ---------------- split-k combine: O = (O0+O1)/(l0+l1) -> shuffled-frag AO ----------
// 160 blocks (32 bh x 5 split q-tiles), 256 threads; ~8MB traffic.
__global__ __launch_bounds__(256) void combine_kernel(const _Float16* __restrict__ Op,
                                                      const float* __restrict__ Lp,
                                                      u16* __restrict__ AO) {
    const int g = blockIdx.x;              // bh*5 + (qt-11)
    const int bh = g / 5, qto = g - bh * 5;
    const int qt = 11 + qto;
    const int b = bh >> 4, h = bh & 15;
    const int q0 = qt * 128;
    const int pi0 = g * 2;
    const _Float16* O0 = Op + (size_t)pi0 * (128 * 64);
    const _Float16* O1 = O0 + 128 * 64;
    const float* L0 = Lp + pi0 * 128;
    const float* L1 = L0 + 128;
    const int tid = threadIdx.x;
#pragma unroll
    for (int rep = 0; rep < 4; ++rep) {
        int idx = rep * 256 + tid;         // 16 chunks x 64 lanes
        int chunk = idx >> 6, lane = idx & 63;
        int rb = chunk >> 1, kt2 = chunk & 1;
        int lm = lane & 15, quad = lane >> 4;
        int q = rb * 16 + lm;
        int d = kt2 * 32 + quad * 8;
        float rl = 1.0f / (L0[q] + L1[q]);
        halfx8 a = *(const halfx8*)&O0[(size_t)q * 64 + d];
        halfx8 c = *(const halfx8*)&O1[(size_t)q * 64 + d];
        uint4 v;
        u32 pk[4];
#pragma unroll
        for (int j = 0; j < 4; ++j) {
            float v0 = ((float)a[2 * j]     + (float)c[2 * j])     * rl;
            float v1 = ((float)a[2 * j + 1] + (float)c[2 * j + 1]) * rl;
            pk[j] = (u32)f2bf(v0) | ((u32)f2bf(v1) << 16);
        }
        v.x = pk[0]; v.y = pk[1]; v.z = pk[2]; v.w = pk[3];
        size_t rowblk = ((size_t)(b * SEQ + q0) >> 4) + rb;
        *(uint4*)&AO[(rowblk * 32 + (h * 2 + kt2)) * 512 + lane * 8] = v;
    }
}

extern "C" void kernel_launch(void* const* d_in, const int* in_sizes, int n_in,
                              void* d_out, int out_size, void* d_ws, size_t ws_size,
                              hipStream_t stream) {
    const float* x   = (const float*)d_in[0];
    const int*   pos = (const int*)d_in[1];
    float* out = (float*)d_out;

    u16* ws = (u16*)d_ws;
    const size_t MD = (size_t)MM * DM;
    const size_t DD = (size_t)DM * DM;
    u16* Xsh = ws;                        // shuffled X; dead after QKV -> reused as AOsh
    u16* Wsh = ws + MD;                   // 4 shuffled weights (q,k,v,o)
    u16* Qbf = ws + MD + 4 * DD;          // Q natural bf16
    u16* Kfb = Qbf + MD;                  // K as QK-A-fragment chunks
    u16* VtB = Kfb + MD;                  // f16 V as PV-A-fragment chunks
    float2* ropetab = (float2*)(VtB + MD);
    _Float16* Vt = (_Float16*)VtB;
    u16* AOsh = Xsh;
    // split-k partials: O f16 overlays the DEAD Wq/Wk/Wv region (5.24MB <= 6MB);
    // lsum f32 after the RoPE table (+160KB)
    _Float16* Opart = (_Float16*)Wsh;
    float* Lpart = (float*)(ropetab + SEQ * 32);

    // prep: bf16 shuffled X + 4 W, RoPE table (one launch)
    prep_kernel<<<dim3(128, 16), 256, 0, stream>>>(
        x, (const float*)d_in[2], (const float*)d_in[3], (const float*)d_in[4],
        (const float*)d_in[5], Xsh, Wsh, pos, ropetab);

    // Q/K/V projections, per-z blocks (z = blockIdx.z), 128x128 tiles, 3 blocks/CU;
    // RoPE fused on Q,K; softmax scale folded into Q; K and V written pre-fragmented
    gemm_s<4, false><<<dim3(32, 8, 3), 256, 0, stream>>>(
        Xsh, Wsh, Qbf, nullptr, Vt, Kfb, ropetab);

    // causal flash attention, split-k (672 balanced items; splits write partials)
    attn_kernel<<<dim3(672), 256, 0, stream>>>(Qbf, Kfb, Vt, AOsh, Opart, Lpart);

    // combine split-k partials into AO
    combine_kernel<<<dim3(160), 256, 0, stream>>>(Opart, Lpart, AOsh);

    // output projection -> fp32 d_out (64x128 tiles, 2 blocks/CU)
    gemm_s<2, true><<<dim3(64, 8, 1), 256, 0, stream>>>(
        AOsh, Wsh + 3 * DD, nullptr, out, nullptr, nullptr, ropetab);
}

// Round 8
// 168.459 us; speedup vs baseline: 1.2286x; 1.0412x over previous
//
#include <hip/hip_runtime.h>
#include <math.h>

typedef unsigned short u16;
typedef unsigned int   u32;
typedef __attribute__((ext_vector_type(8))) short bf16x8;
typedef __attribute__((ext_vector_type(4))) float floatx4;
typedef __attribute__((ext_vector_type(4))) _Float16 halfx4;
typedef __attribute__((ext_vector_type(8))) _Float16 halfx8;
typedef __attribute__((ext_vector_type(2))) unsigned int uintx2;

// B=2, S=2048, D=1024, H=16, Dh=64, M=B*S=4096
#define SEQ 2048
#define DM  1024
#define NH  16
#define DH  64
#define MM  4096
#define QSCALE 0.18033688011112042f   // 0.125 * log2(e), folded into Q

__device__ __forceinline__ u16 f2bf(float f) {
    u32 u = __builtin_bit_cast(u32, f);
    u += 0x7fffu + ((u >> 16) & 1u);
    return (u16)(u >> 16);
}

__device__ __forceinline__ void async16(const void* g, void* l) {
    __builtin_amdgcn_global_load_lds(
        (const __attribute__((address_space(1))) void*)g,
        (__attribute__((address_space(3))) void*)l, 16, 0, 0);
}

// ---------------- prep: fp32 -> bf16 shuffled layout + RoPE table -------------------
// Shuffled layout: tile (rowblk=row/16, ktile=col/32); element [m=lm][k=quad*8+j]
// stored flat at (rowblk*32 + ktile)*512 + lane*8 + j. One dwordx4/lane per fragment.
// First 256 linear blocks additionally fill the RoPE table (2048x32 float2).
__global__ __launch_bounds__(256) void prep_kernel(const float* __restrict__ x,
                                                   const float* __restrict__ w0,
                                                   const float* __restrict__ w1,
                                                   const float* __restrict__ w2,
                                                   const float* __restrict__ w3,
                                                   u16* __restrict__ Xsh,
                                                   u16* __restrict__ Wsh,
                                                   const int* __restrict__ pos,
                                                   float2* __restrict__ tab) {
    const int bid = blockIdx.x, cb = blockIdx.y, tid = threadIdx.x;

    // RoPE table side-job
    int lin = bid * 16 + cb;
    if (lin < 256) {
        int i = lin * 256 + tid;       // 65536 = 2048*32
        int p = i >> 5, d2 = i & 31;
        float freq = __expf(-(float)d2 * (9.2103403719761836f / 32.0f));
        float sv, cv;
        sincosf((float)pos[p] * freq, &sv, &cv);
        tab[i] = make_float2(cv, sv);
    }

    const float* src; u16* dst; int row0;
    if (bid < 64) { src = x; dst = Xsh; row0 = bid * 64; }
    else {
        int wi = (bid - 64) >> 4;
        src = (wi == 0) ? w0 : (wi == 1) ? w1 : (wi == 2) ? w2 : w3;
        dst = Wsh + (size_t)wi * DM * DM;
        row0 = ((bid - 64) & 15) * 64;
    }
    __shared__ __align__(16) u16 t[64 * 64];   // 8-elem chunks XOR-swizzled by row&7
#pragma unroll
    for (int rep = 0; rep < 4; ++rep) {
        int f = rep * 256 + tid;
        int r = f >> 4, c4 = f & 15;
        float4 v = *(const float4*)&src[(size_t)(row0 + r) * DM + cb * 64 + c4 * 4];
        uint2 pk;
        pk.x = (u32)f2bf(v.x) | ((u32)f2bf(v.y) << 16);
        pk.y = (u32)f2bf(v.z) | ((u32)f2bf(v.w) << 16);
        int ch = (c4 >> 1) ^ (r & 7);
        *(uint2*)&t[r * 64 + ch * 8 + (c4 & 1) * 4] = pk;
    }
    __syncthreads();
#pragma unroll
    for (int rep = 0; rep < 2; ++rep) {
        int s = rep * 256 + tid;
        int tile = s >> 6, l = s & 63;
        int mt = tile >> 1, kt = tile & 1, lm = l & 15, quad = l >> 4;
        int m = mt * 16 + lm;
        uint4 v = *(const uint4*)&t[m * 64 + ((kt * 4 + quad) ^ (m & 7)) * 8];
        size_t rowblk = (size_t)(row0 >> 4) + mt;
        size_t ktile  = cb * 2 + kt;
        *(uint4*)&dst[(rowblk * 32 + ktile) * 512 + l * 8] = v;
    }
}

// ---------------- per-z NT GEMM, counted-vmcnt triple-buffer K-loop (T4) ------------
// C_z[M,1024] = A * W_z^T, z = blockIdx.z. Block tile BM x 128 (BM = MREP*32),
// 4 waves (2x2), wave tile (MREP*16) x 64. BK=32, 32 K-steps.
// THREE LDS buffers; per iter: {s_waitcnt vmcnt(LPS); s_barrier} (single asm, memory
// clobber) -> waits ONLY for tile it (tile it+1 stays in flight across the barrier),
// then issue stage(it+2), then MFMA. Prefetch distance ~2 compute phases; the barrier
// never drains the prefetch it just issued (T4: never vmcnt(0) in the main loop).
// Race audit: barrier@t orders compute(t-1) before stage(t+2) overwrites buf
// (t+2)%3==(t-1)%3; per-wave waitcnt+barrier publishes all waves' tile-t chunks;
// tail iter uses vmcnt(0); __syncthreads() after the loop protects epilogue LDS reuse.
// Epilogues: z==0 Q (RoPE+QSCALE, natural bf16); z==1 K (RoPE + LDS-bounce
// transpose -> QK-A-fragment chunks); z==2 V (PV-A-fragment chunks);
// OUTF32 (Wo, MREP=2) writes fp32.
template<int MREP, bool OUTF32>
__global__ __launch_bounds__(256, (MREP == 4) ? 3 : 2)
void gemm_s(const u16* __restrict__ Ash,
            const u16* __restrict__ Wbase,
            u16* __restrict__ qout,
            float* __restrict__ outf,
            _Float16* __restrict__ vtout,
            u16* __restrict__ kout,
            const float2* __restrict__ ropetab) {
    constexpr int BM  = MREP * 32;         // 128 (QKV) or 64 (Wo)
    constexpr int AC  = 2 * MREP;          // A chunks per K-step
    constexpr int APW = AC / 4;            // A chunks staged per wave
    constexpr int STEP = (AC + 8) * 512;   // u16 per LDS buffer
    constexpr int SHN  = 3 * STEP;         // 48KB (QKV; covers 17408-u16 K-scratch) / 36KB (Wo)

    const int z  = blockIdx.z;
    const u16* Wp = Wbase + (size_t)z * (DM * DM);
    const int m0 = blockIdx.x * BM, n0 = blockIdx.y * 128;
    const int tid = threadIdx.x, lane = tid & 63, w = tid >> 6;
    const int wr = w >> 1, wc = w & 1;
    const int lm = lane & 15, quad = lane >> 4;
    const int rb0 = m0 >> 4, cb0 = n0 >> 4;

    __shared__ __align__(16) u16 sh[SHN];

    auto stage = [&](int buf, int it) {
        u16* la = sh + buf * STEP;
        u16* lb = la + AC * 512;
#pragma unroll
        for (int j = 0; j < APW; ++j) {
            int c = w * APW + j;
            async16(Ash + ((size_t)(rb0 + c) * 32 + it) * 512 + lane * 8,
                    &la[c * 512 + lane * 8]);
        }
#pragma unroll
        for (int j = 0; j < 2; ++j) {
            int c = w * 2 + j;
            async16(Wp + ((size_t)(cb0 + c) * 32 + it) * 512 + lane * 8,
                    &lb[c * 512 + lane * 8]);
        }
    };

    floatx4 acc[MREP][4];
    const floatx4 z4 = {0.f, 0.f, 0.f, 0.f};
#pragma unroll
    for (int mt = 0; mt < MREP; ++mt)
#pragma unroll
        for (int nt = 0; nt < 4; ++nt) acc[mt][nt] = z4;

    stage(0, 0);
    stage(1, 1);

    int cur = 0;
    for (int it = 0; it < 32; ++it) {
        // counted wait: tile it landed; tile it+1's loads stay in flight (LPS=APW+2).
        if (it == 31) {
            asm volatile("s_waitcnt vmcnt(0)\n\ts_barrier" ::: "memory");
        } else {
            if constexpr (MREP == 4)
                asm volatile("s_waitcnt vmcnt(4)\n\ts_barrier" ::: "memory");
            else
                asm volatile("s_waitcnt vmcnt(3)\n\ts_barrier" ::: "memory");
        }
        if (it < 30) {
            int pre = cur - 1; if (pre < 0) pre = 2;   // (it+2) % 3
            stage(pre, it + 2);
        }
        const u16* la = sh + cur * STEP;
        const u16* lb = la + AC * 512;
        bf16x8 a[MREP], b[4];
#pragma unroll
        for (int mt = 0; mt < MREP; ++mt)
            a[mt] = *(const bf16x8*)&la[(wr * MREP + mt) * 512 + lane * 8];
#pragma unroll
        for (int nt = 0; nt < 4; ++nt)
            b[nt] = *(const bf16x8*)&lb[(wc * 4 + nt) * 512 + lane * 8];
#pragma unroll
        for (int mt = 0; mt < MREP; ++mt)
#pragma unroll
            for (int nt = 0; nt < 4; ++nt)
                acc[mt][nt] = __builtin_amdgcn_mfma_f32_16x16x32_bf16(
                    a[mt], b[nt], acc[mt][nt], 0, 0, 0);
        ++cur; if (cur == 3) cur = 0;
    }
    __syncthreads();   // all waves done with sh before epilogue reuse (z==1 scratch)

    if constexpr (OUTF32) {
#pragma unroll
        for (int mt = 0; mt < MREP; ++mt)
#pragma unroll
            for (int r = 0; r < 4; ++r) {
                int row = m0 + wr * (MREP * 16) + mt * 16 + quad * 4 + r;
#pragma unroll
                for (int nt = 0; nt < 4; ++nt) {
                    int col = n0 + wc * 64 + nt * 16 + lm;
                    outf[(size_t)row * DM + col] = acc[mt][nt][r];
                }
            }
        return;
    } else {
        if (z == 0) {
            // Q: RoPE + QSCALE, natural bf16 (pair store via lane-parity)
#pragma unroll
            for (int mt = 0; mt < MREP; ++mt)
#pragma unroll
                for (int r = 0; r < 4; ++r) {
                    int row = m0 + wr * (MREP * 16) + mt * 16 + quad * 4 + r;
#pragma unroll
                    for (int nt = 0; nt < 4; ++nt) {
                        int col = n0 + wc * 64 + nt * 16 + lm;
                        float v  = acc[mt][nt][r];
                        float pv = __shfl_xor(v, 1);
                        float2 cs = ropetab[(row & (SEQ - 1)) * 32 + ((col & 63) >> 1)];
                        v = (lm & 1) ? fmaf(pv, cs.y, v * cs.x) : fmaf(v, cs.x, -pv * cs.y);
                        v *= QSCALE;
                        float hv = __shfl_xor(v, 1);
                        if (!(lm & 1)) {
                            u32 pk = (u32)f2bf(v) | ((u32)f2bf(hv) << 16);
                            *(u32*)&qout[(size_t)row * DM + col] = pk;
                        }
                    }
                }
        } else if (z == 1) {
            if constexpr (MREP == 4) {
                // K: RoPE, LDS-bounce transpose into QK A-fragment chunks.
                // Chunk = ((bh*128 + sblk)*2 + ks2), 512 bf16;
                // element lane*8+j = K[key=sblk*16+lm][kd=ks2*32+quad*8+j].
                u16* t = sh;   // 128 x 136 u16 scratch (union over stage buffers)
#pragma unroll
                for (int mt = 0; mt < MREP; ++mt)
#pragma unroll
                    for (int r = 0; r < 4; ++r) {
                        int rl  = wr * 64 + mt * 16 + quad * 4 + r;
                        int row = m0 + rl;
#pragma unroll
                        for (int nt = 0; nt < 4; ++nt) {
                            int cl  = wc * 64 + nt * 16 + lm;
                            int col = n0 + cl;
                            float v  = acc[mt][nt][r];
                            float pv = __shfl_xor(v, 1);
                            float2 cs = ropetab[(row & (SEQ - 1)) * 32 + ((col & 63) >> 1)];
                            v = (lm & 1) ? fmaf(pv, cs.y, v * cs.x) : fmaf(v, cs.x, -pv * cs.y);
                            t[rl * 136 + cl] = f2bf(v);
                        }
                    }
                __syncthreads();
                {
                    int bb = m0 >> 11;
                    int sblk0 = (m0 & (SEQ - 1)) >> 4;
                    int h0 = n0 >> 6;
#pragma unroll
                    for (int j = 0; j < 8; ++j) {
                        int c = w * 8 + j;          // hloc(1b) | sblkl(3b) | ks2(1b)
                        int hloc = c >> 4, sblkl = (c >> 1) & 7, ks2 = c & 1;
                        uint4 v4 = *(const uint4*)&t[(sblkl * 16 + lm) * 136 + hloc * 64 + ks2 * 32 + quad * 8];
                        size_t chunk = ((size_t)(bb * NH + h0 + hloc) * 128 + sblk0 + sblkl) * 2 + ks2;
                        *(uint4*)&kout[chunk * 512 + lane * 8] = v4;
                    }
                }
            }
        } else {
            if constexpr (MREP == 4) {
                // V: PV A-fragment chunks. Chunk = ((b*NH+h)*128 + sblk)*4 + dblk,
                // 256 halves; element lane*4+j = V[d=dblk*16+lm][key=sblk*16+quad*4+j].
#pragma unroll
                for (int mt = 0; mt < MREP; ++mt) {
                    int row = m0 + wr * 64 + mt * 16;    // + quad*4+r in lane
                    int b = row >> 11;
                    int sblk = (row & (SEQ - 1)) >> 4;
#pragma unroll
                    for (int nt = 0; nt < 4; ++nt) {
                        int col = n0 + wc * 64 + nt * 16;  // + lm in lane
                        int h = col >> 6;
                        int dblk = (col & 63) >> 4;
                        size_t chunk = ((size_t)(b * NH + h) * 128 + sblk) * 4 + dblk;
                        uint2 pk;
                        pk.x = __builtin_bit_cast(u32, __builtin_amdgcn_cvt_pkrtz(acc[mt][nt][0], acc[mt][nt][1]));
                        pk.y = __builtin_bit_cast(u32, __builtin_amdgcn_cvt_pkrtz(acc[mt][nt][2], acc[mt][nt][3]));
                        *(uint2*)&vtout[chunk * 256 + lane * 4] = pk;
                    }
                }
            }
        }
    }
}

// ---------------- causal flash attention, split-k, fragment-linear LDS --------------
// Work items per bh (21): singles qt=0..10 (full k-range), and qt=11..15 split into
// two k-range halves (flash split-k: no running max -> partials simply add).
// Item table ordered descending by iteration count for dispatch balance; grid 672.
// Block: 4 waves x 32 q-rows; k-tile 128, double-buffered, ONE barrier per k-tile.
// ALL LDS accesses fragment-linear (chunk + lane*16B/8B): zero bank conflicts, zero
// per-read address VALU. K/V arrive PRE-FRAGMENTED from the QKV GEMM (linear copy).
// exp2 via __builtin_amdgcn_exp2f (raw v_exp_f32; libm exp2f = ~15 VALU ops each).
// Row-sum rides the matrix pipe via a ones-fragment MFMA (o5).
// Singles write AO (shuffled-frag); splits write unnormalized O-partial f16 + lsum.
// itab entry: qt | k0<<4 | k1<<8 | split<<13 | part<<14
static __device__ const u16 itab[21] = {
    0x0B0A,                                  // s10 (11 iters)
    0x0A09,                                  // s9  (10)
    0x0908,                                  // s8  (9)
    0x280F, 0x708F, 0x6F7E, 0x0807,          // 15p0,15p1,14p1,s7 (8)
    0x270E, 0x270D, 0x6E7D, 0x6D6C, 0x0706,  // 14p0,13p0,13p1,12p1,s6 (7)
    0x260C, 0x260B, 0x6C6B, 0x0605,          // 12p0,11p0,11p1,s5 (6)
    0x0504, 0x0403, 0x0302, 0x0201, 0x0100   // s4..s0
};

__global__ __launch_bounds__(256, 2) void attn_kernel(const u16* __restrict__ Q,
                                                      const u16* __restrict__ Kf,
                                                      const _Float16* __restrict__ Vf,
                                                      u16* __restrict__ AO,
                                                      _Float16* __restrict__ Opart,
                                                      float* __restrict__ Lpart) {
    const int u  = blockIdx.x;
    const int e  = itab[u >> 5];
    const int bh = u & 31;
    const int qt = e & 15;
    const int k0 = (e >> 4) & 15;
    const int k1 = (e >> 8) & 31;
    const bool split = (e >> 13) & 1;
    const int part = e >> 14;
    const int b  = bh >> 4, h = bh & 15;
    const int q0 = qt * 128;
    const int tid = threadIdx.x, w = tid >> 6, lane = tid & 63;
    const int lm = lane & 15, quad = lane >> 4;

    __shared__ __align__(16) u16      lsK[2][16 * 512];   // 2 x 16KB: 16 K-frag chunks
    __shared__ __align__(16) _Float16 lsV[2][32 * 256];   // 2 x 16KB: 32 V-frag chunks

    bf16x8 qb[2][2];              // [qi][ks]; wave w owns q-rows w*32 .. w*32+31
#pragma unroll
    for (int qi = 0; qi < 2; ++qi)
#pragma unroll
        for (int ks = 0; ks < 2; ++ks)
            qb[qi][ks] = *(const bf16x8*)
                &Q[(size_t)(b * SEQ + q0 + w * 32 + qi * 16 + lm) * DM + h * DH + ks * 32 + quad * 8];

    const floatx4 z4 = {0.f, 0.f, 0.f, 0.f};
    floatx4 o[2][4];              // O^T[d][q]: d = dt*16+quad*4+r, q = lm
    floatx4 o5[2];                // row-sum accumulator (ones-row MFMA)
#pragma unroll
    for (int qi = 0; qi < 2; ++qi) {
#pragma unroll
        for (int dt = 0; dt < 4; ++dt) o[qi][dt] = z4;
        o5[qi] = z4;
    }

    // pre-fragmented K: 256 chunks/bh (1KB each); k-tile kt = chunks [kt*16, +16)
    const u16*      Kb = Kf + (size_t)bh * (256 * 512);
    // pre-fragmented V: 512 chunks/bh (512B each); k-tile kt = chunks [kt*32, +32)
    const _Float16* Vb = Vf + (size_t)bh * (128 * 4 * 256);

    auto stageKV = [&](int buf, int kt) {
#pragma unroll
        for (int j = 0; j < 4; ++j) {
            // K: 16KB linear (wave w copies chunks w*4..w*4+3)
            int kc = w * 4 + j;
            async16(Kb + ((size_t)kt * 16 + kc) * 512 + lane * 8,
                    &lsK[buf][kc * 512 + lane * 8]);
            // V: 16KB linear (wave w copies quarter w, 1KB per async16)
            int off = w * 2048 + j * 512 + lane * 8;
            async16(Vb + (size_t)kt * 8192 + off, &lsV[buf][off]);
        }
    };

    stageKV(k0 & 1, k0);
    const halfx4 ones = {(_Float16)1.f, (_Float16)1.f, (_Float16)1.f, (_Float16)1.f};

    for (int kt = k0; kt < k1; ++kt) {
        __syncthreads();
        if (kt + 1 < k1) stageKV((kt + 1) & 1, kt + 1);
        const u16*      Lk = lsK[kt & 1];
        const _Float16* Lv = lsV[kt & 1];

        // QK^T: fragment-linear ka, each read feeds both q-fragments
        floatx4 s4[2][8];
#pragma unroll
        for (int qi = 0; qi < 2; ++qi)
#pragma unroll
            for (int st = 0; st < 8; ++st) s4[qi][st] = z4;
#pragma unroll
        for (int ks = 0; ks < 2; ++ks)
#pragma unroll
            for (int st = 0; st < 8; ++st) {
                bf16x8 ka = *(const bf16x8*)&Lk[(st * 2 + ks) * 512 + lane * 8];
#pragma unroll
                for (int qi = 0; qi < 2; ++qi)
                    s4[qi][st] = __builtin_amdgcn_mfma_f32_16x16x32_bf16(ka, qb[qi][ks], s4[qi][st], 0, 0, 0);
            }

        const bool diag = (kt == qt);
#pragma unroll
        for (int st = 0; st < 8; ++st) {
            halfx4 pb2[2];
#pragma unroll
            for (int qi = 0; qi < 2; ++qi) {
#pragma unroll
                for (int r = 0; r < 4; ++r) {
                    float v = s4[qi][st][r];
                    if (diag) {
                        int keyloc = st * 16 + quad * 4 + r;
                        if (keyloc > w * 32 + qi * 16 + lm) v = -1e30f;
                    }
                    s4[qi][st][r] = __builtin_amdgcn_exp2f(v);   // raw v_exp_f32
                }
                uintx2 pk2;
                pk2.x = __builtin_bit_cast(u32, __builtin_amdgcn_cvt_pkrtz(s4[qi][st][0], s4[qi][st][1]));
                pk2.y = __builtin_bit_cast(u32, __builtin_amdgcn_cvt_pkrtz(s4[qi][st][2], s4[qi][st][3]));
                pb2[qi] = __builtin_bit_cast(halfx4, pk2);
            }
            // PV: fragment-linear va, feeds both q-fragments; lsum via ones-MFMA
#pragma unroll
            for (int dt = 0; dt < 4; ++dt) {
                halfx4 va = *(const halfx4*)&Lv[(st * 4 + dt) * 256 + lane * 4];
#pragma unroll
                for (int qi = 0; qi < 2; ++qi)
                    o[qi][dt] = __builtin_amdgcn_mfma_f32_16x16x16f16(va, pb2[qi], o[qi][dt], 0, 0, 0);
            }
#pragma unroll
            for (int qi = 0; qi < 2; ++qi)
                o5[qi] = __builtin_amdgcn_mfma_f32_16x16x16f16(ones, pb2[qi], o5[qi], 0, 0, 0);
        }
    }

    if (split) {
        // unnormalized O^T partial (f16, |o| <~ 1e4 << 65504) + lsum partial
        const int pi = (bh * 5 + (qt - 11)) * 2 + part;
        _Float16* Od = Opart + (size_t)pi * (128 * 64);
#pragma unroll
        for (int qi = 0; qi < 2; ++qi) {
            const int q = w * 32 + qi * 16 + lm;
#pragma unroll
            for (int dt = 0; dt < 4; ++dt) {
                uintx2 pk2;
                pk2.x = __builtin_bit_cast(u32, __builtin_amdgcn_cvt_pkrtz(o[qi][dt][0], o[qi][dt][1]));
                pk2.y = __builtin_bit_cast(u32, __builtin_amdgcn_cvt_pkrtz(o[qi][dt][2], o[qi][dt][3]));
                *(uintx2*)&Od[(size_t)q * 64 + dt * 16 + quad * 4] = pk2;
            }
            if (quad == 0) Lpart[pi * 128 + q] = o5[qi][0];
        }
        return;
    }

    // o5[qi] rows all hold the full row-sum for q = lm (ones-row MFMA sums all keys)
    float rl[2] = {1.0f / o5[0][0], 1.0f / o5[1][0]};

    // epilogue: O^T (reg) -> LDS (swizzled natural [q][d]) -> shuffled-frag AO store
    __syncthreads();                       // all waves done with lsK/lsV
    u16* eb = (u16*)&lsK[0][0];            // 128x64 bf16 = 16 KB (= lsK buffer 0)
#pragma unroll
    for (int qi = 0; qi < 2; ++qi) {
        const int q = w * 32 + qi * 16 + lm;
#pragma unroll
        for (int dt = 0; dt < 4; ++dt) {
            uint2 pk;
            pk.x = (u32)f2bf(o[qi][dt][0] * rl[qi]) | ((u32)f2bf(o[qi][dt][1] * rl[qi]) << 16);
            pk.y = (u32)f2bf(o[qi][dt][2] * rl[qi]) | ((u32)f2bf(o[qi][dt][3] * rl[qi]) << 16);
            int ch = (dt * 2 + (quad >> 1)) ^ (lm & 7);
            *(uint2*)&eb[q * 64 + ch * 8 + (quad & 1) * 4] = pk;
        }
    }
    __syncthreads();
    const size_t rowblk0 = (size_t)((b * SEQ + q0) >> 4);
#pragma unroll
    for (int rbi = 0; rbi < 2; ++rbi) {
#pragma unroll
        for (int kt = 0; kt < 2; ++kt) {
            uint4 v = *(const uint4*)&eb[((w * 2 + rbi) * 16 + lm) * 64 + ((kt * 4 + quad) ^ (lm & 7)) * 8];
            *(uint4*)&AO[((rowblk0 + w * 2 + rbi) * 32 + (h * 2 + kt)) * 512 + lane * 8] = v;
        }
    }
}

// ---------------- split-k combine: O = (O0+O1)/(l0+l1) -> shuffled-frag AO ----------
// 160 blocks (32 bh x 5 split q-tiles), 256 threads; ~8MB traffic.
__global__ __launch_bounds__(256) void combine_kernel(const _Float16* __restrict__ Op,
                                                      const float* __restrict__ Lp,
                                                      u16* __restrict__ AO) {
    const int g = blockIdx.x;              // bh*5 + (qt-11)
    const int bh = g / 5, qto = g - bh * 5;
    const int qt = 11 + qto;
    const int b = bh >> 4, h = bh & 15;
    const int q0 = qt * 128;
    const int pi0 = g * 2;
    const _Float16* O0 = Op + (size_t)pi0 * (128 * 64);
    const _Float16* O1 = O0 + 128 * 64;
    const float* L0 = Lp + pi0 * 128;
    const float* L1 = L0 + 128;
    const int tid = threadIdx.x;
#pragma unroll
    for (int rep = 0; rep < 4; ++rep) {
        int idx = rep * 256 + tid;         // 16 chunks x 64 lanes
        int chunk = idx >> 6, lane = idx & 63;
        int rb = chunk >> 1, kt2 = chunk & 1;
        int lm = lane & 15, quad = lane >> 4;
        int q = rb * 16 + lm;
        int d = kt2 * 32 + quad * 8;
        float rl = 1.0f / (L0[q] + L1[q]);
        halfx8 a = *(const halfx8*)&O0[(size_t)q * 64 + d];
        halfx8 c = *(const halfx8*)&O1[(size_t)q * 64 + d];
        uint4 v;
        u32 pk[4];
#pragma unroll
        for (int j = 0; j < 4; ++j) {
            float v0 = ((float)a[2 * j]     + (float)c[2 * j])     * rl;
            float v1 = ((float)a[2 * j + 1] + (float)c[2 * j + 1]) * rl;
            pk[j] = (u32)f2bf(v0) | ((u32)f2bf(v1) << 16);
        }
        v.x = pk[0]; v.y = pk[1]; v.z = pk[2]; v.w = pk[3];
        size_t rowblk = ((size_t)(b * SEQ + q0) >> 4) + rb;
        *(uint4*)&AO[(rowblk * 32 + (h * 2 + kt2)) * 512 + lane * 8] = v;
    }
}

extern "C" void kernel_launch(void* const* d_in, const int* in_sizes, int n_in,
                              void* d_out, int out_size, void* d_ws, size_t ws_size,
                              hipStream_t stream) {
    const float* x   = (const float*)d_in[0];
    const int*   pos = (const int*)d_in[1];
    float* out = (float*)d_out;

    u16* ws = (u16*)d_ws;
    const size_t MD = (size_t)MM * DM;
    const size_t DD = (size_t)DM * DM;
    u16* Xsh = ws;                        // shuffled X; dead after QKV -> reused as AOsh
    u16* Wsh = ws + MD;                   // 4 shuffled weights (q,k,v,o)
    u16* Qbf = ws + MD + 4 * DD;          // Q natural bf16
    u16* Kfb = Qbf + MD;                  // K as QK-A-fragment chunks
    u16* VtB = Kfb + MD;                  // f16 V as PV-A-fragment chunks
    float2* ropetab = (float2*)(VtB + MD);
    _Float16* Vt = (_Float16*)VtB;
    u16* AOsh = Xsh;
    // split-k partials: O f16 overlays the DEAD Wq/Wk/Wv region (5.24MB <= 6MB);
    // lsum f32 after the RoPE table (+160KB)
    _Float16* Opart = (_Float16*)Wsh;
    float* Lpart = (float*)(ropetab + SEQ * 32);

    // prep: bf16 shuffled X + 4 W, RoPE table (one launch)
    prep_kernel<<<dim3(128, 16), 256, 0, stream>>>(
        x, (const float*)d_in[2], (const float*)d_in[3], (const float*)d_in[4],
        (const float*)d_in[5], Xsh, Wsh, pos, ropetab);

    // Q/K/V projections, per-z blocks (z = blockIdx.z), 128x128 tiles, 3 blocks/CU;
    // counted-vmcnt triple-buffer K-loop; RoPE fused on Q,K; K/V written pre-fragmented
    gemm_s<4, false><<<dim3(32, 8, 3), 256, 0, stream>>>(
        Xsh, Wsh, Qbf, nullptr, Vt, Kfb, ropetab);

    // causal flash attention, split-k (672 balanced items; splits write partials)
    attn_kernel<<<dim3(672), 256, 0, stream>>>(Qbf, Kfb, Vt, AOsh, Opart, Lpart);

    // combine split-k partials into AO
    combine_kernel<<<dim3(160), 256, 0, stream>>>(Opart, Lpart, AOsh);

    // output projection -> fp32 d_out (64x128 tiles, 2 blocks/CU)
    gemm_s<2, true><<<dim3(64, 8, 1), 256, 0, stream>>>(
        AOsh, Wsh + 3 * DD, nullptr, out, nullptr, nullptr, ropetab);
}